// Round 8
// baseline (261.252 us; speedup 1.0000x reference)
//
#include <hip/hip_runtime.h>
#include <hip/hip_bf16.h>
#include <math.h>

#define BB 64
#define NLAYER 2

typedef __attribute__((ext_vector_type(8))) short bfrag;
typedef __attribute__((ext_vector_type(4))) float f4_t;

__device__ __forceinline__ float dot4(float4 a, float4 b, float acc) {
    acc = fmaf(a.x, b.x, acc);
    acc = fmaf(a.y, b.y, acc);
    acc = fmaf(a.z, b.z, acc);
    acc = fmaf(a.w, b.w, acc);
    return acc;
}

// fp32 -> bf16 round-to-nearest-even
__device__ __forceinline__ ushort f2bf(float f) {
    uint32_t u = __float_as_uint(f);
    uint32_t r = (u + 0x7FFFu + ((u >> 16) & 1u)) >> 16;
    return (ushort)r;
}
__device__ __forceinline__ float bf2f(ushort u) {
    return __uint_as_float(((uint32_t)u) << 16);
}

// ---------------------------------------------------------------------------
// Weight conversion fp32 -> bf16 into one ws region.
// offsets (elements): fp:0, qkv:65536, aow:458752, f1:589824, f2:851968,
// out:1114112; total 1179648. 2048 elems/block, 576 blocks.
// ---------------------------------------------------------------------------
__global__ __launch_bounds__(256) void k_cvt(
    const float* __restrict__ fp_w, const float* __restrict__ qkv_w,
    const float* __restrict__ aow, const float* __restrict__ f1w,
    const float* __restrict__ f2w, const float* __restrict__ outw,
    ushort* __restrict__ dst) {
    const int g = blockIdx.x;
    const size_t idx = (size_t)g * 2048 + threadIdx.x * 8;
    const float* src;
    size_t base;
    if (g < 32)       { src = fp_w;  base = 0; }
    else if (g < 224) { src = qkv_w; base = 65536; }
    else if (g < 288) { src = aow;   base = 458752; }
    else if (g < 416) { src = f1w;   base = 589824; }
    else if (g < 544) { src = f2w;   base = 851968; }
    else              { src = outw;  base = 1114112; }
    const float4* s4 = reinterpret_cast<const float4*>(src + (idx - base));
    float4 a = s4[0], b = s4[1];
    bfrag o;
    o[0] = (short)f2bf(a.x); o[1] = (short)f2bf(a.y);
    o[2] = (short)f2bf(a.z); o[3] = (short)f2bf(a.w);
    o[4] = (short)f2bf(b.x); o[5] = (short)f2bf(b.y);
    o[6] = (short)f2bf(b.z); o[7] = (short)f2bf(b.w);
    *reinterpret_cast<bfrag*>(dst + idx) = o;
}

// ---------------------------------------------------------------------------
// bf16 MFMA GEMM, BM=64 BN=128, register prefetch, swapped mfma.
// EPI: 0 none, 2 relu, 3 corr (/255, nan->0, clip). grid (M/64, N/128, nb).
// ---------------------------------------------------------------------------
template <int EPI, bool WF32, bool WBF>
__global__ __launch_bounds__(256) void k_mm(
    const ushort* __restrict__ A, const ushort* __restrict__ B,
    const float* __restrict__ bias, float* __restrict__ C,
    ushort* __restrict__ Cb, int K, int N,
    size_t aStr, size_t bStr, size_t cStr) {
    __shared__ __align__(16) ushort As[64 * 72];
    __shared__ __align__(16) ushort Bs[128 * 72];
    const int tid = threadIdx.x;
    const int m0 = blockIdx.x * 64, n0 = blockIdx.y * 128;
    const size_t z = blockIdx.z;
    const int w = tid >> 6, lane = tid & 63;
    const int wm = w >> 1, wn = w & 1;
    const int fr = lane & 15, fq = lane >> 4;

    const int arow = tid >> 2, akc = (tid & 3) * 16;
    const ushort* aS = A + z * aStr + (size_t)(m0 + arow) * K + akc;
    ushort* aD = &As[arow * 72 + akc];
    const int brow = tid >> 1, bkc = (tid & 1) * 32;
    const ushort* bS = B + z * bStr + (size_t)(n0 + brow) * K + bkc;
    ushort* bD = &Bs[brow * 72 + bkc];

    f4_t acc[2][4];
#pragma unroll
    for (int i = 0; i < 2; ++i)
#pragma unroll
        for (int j = 0; j < 4; ++j) acc[i][j] = (f4_t)0.f;

    bfrag ra0, ra1, rb0, rb1, rb2, rb3;
    {
        const bfrag* ap = reinterpret_cast<const bfrag*>(aS);
        ra0 = ap[0]; ra1 = ap[1];
        const bfrag* bp = reinterpret_cast<const bfrag*>(bS);
        rb0 = bp[0]; rb1 = bp[1]; rb2 = bp[2]; rb3 = bp[3];
    }

    for (int k0 = 0; k0 < K; k0 += 64) {
        reinterpret_cast<bfrag*>(aD)[0] = ra0;
        reinterpret_cast<bfrag*>(aD)[1] = ra1;
        reinterpret_cast<bfrag*>(bD)[0] = rb0;
        reinterpret_cast<bfrag*>(bD)[1] = rb1;
        reinterpret_cast<bfrag*>(bD)[2] = rb2;
        reinterpret_cast<bfrag*>(bD)[3] = rb3;
        __syncthreads();
        if (k0 + 64 < K) {
            const bfrag* ap = reinterpret_cast<const bfrag*>(aS + k0 + 64);
            ra0 = ap[0]; ra1 = ap[1];
            const bfrag* bp = reinterpret_cast<const bfrag*>(bS + k0 + 64);
            rb0 = bp[0]; rb1 = bp[1]; rb2 = bp[2]; rb3 = bp[3];
        }
#pragma unroll
        for (int ks = 0; ks < 2; ++ks) {
            const int kb = ks * 32 + fq * 8;
            bfrag af[2], bf[4];
#pragma unroll
            for (int fm = 0; fm < 2; ++fm)
                af[fm] = *reinterpret_cast<const bfrag*>(
                    &As[(wm * 32 + fm * 16 + fr) * 72 + kb]);
#pragma unroll
            for (int fn = 0; fn < 4; ++fn)
                bf[fn] = *reinterpret_cast<const bfrag*>(
                    &Bs[(wn * 64 + fn * 16 + fr) * 72 + kb]);
#pragma unroll
            for (int fm = 0; fm < 2; ++fm)
#pragma unroll
                for (int fn = 0; fn < 4; ++fn)
                    acc[fm][fn] = __builtin_amdgcn_mfma_f32_16x16x32_bf16(
                        bf[fn], af[fm], acc[fm][fn], 0, 0, 0);
        }
        __syncthreads();
    }

#pragma unroll
    for (int fn = 0; fn < 4; ++fn) {
        const int col0 = n0 + wn * 64 + fn * 16 + fq * 4;
        float4 bv = make_float4(0.f, 0.f, 0.f, 0.f);
        if (EPI != 3 && bias != nullptr)
            bv = *reinterpret_cast<const float4*>(&bias[col0]);
#pragma unroll
        for (int fm = 0; fm < 2; ++fm) {
            const int row = m0 + wm * 32 + fm * 16 + fr;
            float v0 = acc[fm][fn][0] + bv.x;
            float v1 = acc[fm][fn][1] + bv.y;
            float v2 = acc[fm][fn][2] + bv.z;
            float v3 = acc[fm][fn][3] + bv.w;
            if (EPI == 2) {
                v0 = fmaxf(v0, 0.f); v1 = fmaxf(v1, 0.f);
                v2 = fmaxf(v2, 0.f); v3 = fmaxf(v3, 0.f);
            }
            if (EPI == 3) {
                v0 = acc[fm][fn][0] * (1.f / 255.f);
                v1 = acc[fm][fn][1] * (1.f / 255.f);
                v2 = acc[fm][fn][2] * (1.f / 255.f);
                v3 = acc[fm][fn][3] * (1.f / 255.f);
                if (v0 != v0) v0 = 0.f;
                if (v1 != v1) v1 = 0.f;
                if (v2 != v2) v2 = 0.f;
                if (v3 != v3) v3 = 0.f;
                v0 = fminf(1.f, fmaxf(-1.f, v0));
                v1 = fminf(1.f, fmaxf(-1.f, v1));
                v2 = fminf(1.f, fmaxf(-1.f, v2));
                v3 = fminf(1.f, fmaxf(-1.f, v3));
            }
            const size_t o = cStr * z + (size_t)row * N + col0;
            if (WF32) {
                float4 fv = {v0, v1, v2, v3};
                *reinterpret_cast<float4*>(&C[o]) = fv;
            }
            if (WBF) {
                ushort4 uv;
                uv.x = f2bf(v0); uv.y = f2bf(v1);
                uv.z = f2bf(v2); uv.w = f2bf(v3);
                *reinterpret_cast<ushort4*>(&Cb[o]) = uv;
            }
        }
    }
}

// ---------------------------------------------------------------------------
// Fused GEMM + bias (+bf16 residual) + LayerNorm(256) (+leaky) -> bf16 only.
// BM=32, BN=256=N, 256 threads = 4 waves; + register prefetch.
// ---------------------------------------------------------------------------
template <int ACT, bool RES>
__global__ __launch_bounds__(256) void k_mmln(
    const ushort* __restrict__ A, const ushort* __restrict__ W,
    const float* __restrict__ bias, const ushort* __restrict__ res,
    const float* __restrict__ g, const float* __restrict__ bt,
    ushort* __restrict__ outb, int K) {
    __shared__ __align__(16) ushort As[32 * 72];
    __shared__ __align__(16) ushort Bs[256 * 72];
    __shared__ float redS[32][4];
    __shared__ float redQ[32][4];
    const int tid = threadIdx.x;
    const int m0 = blockIdx.x * 32;
    const int w = tid >> 6, lane = tid & 63;
    const int fr = lane & 15, fq = lane >> 4;

    const int arow = tid >> 3, akc = (tid & 7) * 8;
    const ushort* aS = A + (size_t)(m0 + arow) * K + akc;
    ushort* aD = &As[arow * 72 + akc];
    const int brow = tid >> 1, bkc = (tid & 1) * 32;
    const ushort* bS0 = W + (size_t)brow * K + bkc;
    const ushort* bS1 = W + (size_t)(brow + 128) * K + bkc;
    ushort* bD0 = &Bs[brow * 72 + bkc];
    ushort* bD1 = &Bs[(brow + 128) * 72 + bkc];

    f4_t acc[2][4];
#pragma unroll
    for (int i = 0; i < 2; ++i)
#pragma unroll
        for (int j = 0; j < 4; ++j) acc[i][j] = (f4_t)0.f;

    bfrag ra, rb0, rb1, rb2, rb3, rc0, rc1, rc2, rc3;
    {
        ra = *reinterpret_cast<const bfrag*>(aS);
        const bfrag* bp0 = reinterpret_cast<const bfrag*>(bS0);
        rb0 = bp0[0]; rb1 = bp0[1]; rb2 = bp0[2]; rb3 = bp0[3];
        const bfrag* bp1 = reinterpret_cast<const bfrag*>(bS1);
        rc0 = bp1[0]; rc1 = bp1[1]; rc2 = bp1[2]; rc3 = bp1[3];
    }

    for (int k0 = 0; k0 < K; k0 += 64) {
        *reinterpret_cast<bfrag*>(aD) = ra;
        reinterpret_cast<bfrag*>(bD0)[0] = rb0;
        reinterpret_cast<bfrag*>(bD0)[1] = rb1;
        reinterpret_cast<bfrag*>(bD0)[2] = rb2;
        reinterpret_cast<bfrag*>(bD0)[3] = rb3;
        reinterpret_cast<bfrag*>(bD1)[0] = rc0;
        reinterpret_cast<bfrag*>(bD1)[1] = rc1;
        reinterpret_cast<bfrag*>(bD1)[2] = rc2;
        reinterpret_cast<bfrag*>(bD1)[3] = rc3;
        __syncthreads();
        if (k0 + 64 < K) {
            ra = *reinterpret_cast<const bfrag*>(aS + k0 + 64);
            const bfrag* bp0 = reinterpret_cast<const bfrag*>(bS0 + k0 + 64);
            rb0 = bp0[0]; rb1 = bp0[1]; rb2 = bp0[2]; rb3 = bp0[3];
            const bfrag* bp1 = reinterpret_cast<const bfrag*>(bS1 + k0 + 64);
            rc0 = bp1[0]; rc1 = bp1[1]; rc2 = bp1[2]; rc3 = bp1[3];
        }
#pragma unroll
        for (int ks = 0; ks < 2; ++ks) {
            const int kb = ks * 32 + fq * 8;
            bfrag af[2], bf[4];
#pragma unroll
            for (int fm = 0; fm < 2; ++fm)
                af[fm] = *reinterpret_cast<const bfrag*>(
                    &As[(fm * 16 + fr) * 72 + kb]);
#pragma unroll
            for (int fn = 0; fn < 4; ++fn)
                bf[fn] = *reinterpret_cast<const bfrag*>(
                    &Bs[(w * 64 + fn * 16 + fr) * 72 + kb]);
#pragma unroll
            for (int fm = 0; fm < 2; ++fm)
#pragma unroll
                for (int fn = 0; fn < 4; ++fn)
                    acc[fm][fn] = __builtin_amdgcn_mfma_f32_16x16x32_bf16(
                        bf[fn], af[fm], acc[fm][fn], 0, 0, 0);
        }
        __syncthreads();
    }

#pragma unroll
    for (int fn = 0; fn < 4; ++fn) {
        const int col0 = w * 64 + fn * 16 + fq * 4;
        const float4 bv = *reinterpret_cast<const float4*>(&bias[col0]);
#pragma unroll
        for (int fm = 0; fm < 2; ++fm) {
            const int row = fm * 16 + fr;
            float r0 = 0.f, r1 = 0.f, r2 = 0.f, r3 = 0.f;
            if (RES) {
                ushort4 r4 = *reinterpret_cast<const ushort4*>(
                    &res[(size_t)(m0 + row) * 256 + col0]);
                r0 = bf2f(r4.x); r1 = bf2f(r4.y);
                r2 = bf2f(r4.z); r3 = bf2f(r4.w);
            }
            acc[fm][fn][0] += bv.x + r0;
            acc[fm][fn][1] += bv.y + r1;
            acc[fm][fn][2] += bv.z + r2;
            acc[fm][fn][3] += bv.w + r3;
        }
    }
#pragma unroll
    for (int fm = 0; fm < 2; ++fm) {
        float s = 0.f, q = 0.f;
#pragma unroll
        for (int fn = 0; fn < 4; ++fn)
#pragma unroll
            for (int j = 0; j < 4; ++j) {
                const float v = acc[fm][fn][j];
                s += v;
                q += v * v;
            }
        s += __shfl_xor(s, 16); q += __shfl_xor(q, 16);
        s += __shfl_xor(s, 32); q += __shfl_xor(q, 32);
        if (fq == 0) {
            redS[fm * 16 + fr][w] = s;
            redQ[fm * 16 + fr][w] = q;
        }
    }
    __syncthreads();
#pragma unroll
    for (int fm = 0; fm < 2; ++fm) {
        const int row = fm * 16 + fr;
        const float S = redS[row][0] + redS[row][1] + redS[row][2] + redS[row][3];
        const float Q = redQ[row][0] + redQ[row][1] + redQ[row][2] + redQ[row][3];
        const float mean = S * (1.f / 256.f);
        const float var = Q * (1.f / 256.f) - mean * mean;
        const float rstd = rsqrtf(fmaxf(var, 0.f) + 1e-5f);
        const size_t rowoff = (size_t)(m0 + row) * 256;
#pragma unroll
        for (int fn = 0; fn < 4; ++fn) {
            const int col0 = w * 64 + fn * 16 + fq * 4;
            const float4 g4 = *reinterpret_cast<const float4*>(&g[col0]);
            const float4 b4 = *reinterpret_cast<const float4*>(&bt[col0]);
            float v0 = (acc[fm][fn][0] - mean) * rstd * g4.x + b4.x;
            float v1 = (acc[fm][fn][1] - mean) * rstd * g4.y + b4.y;
            float v2 = (acc[fm][fn][2] - mean) * rstd * g4.z + b4.z;
            float v3 = (acc[fm][fn][3] - mean) * rstd * g4.w + b4.w;
            if (ACT == 1) {
                v0 = v0 >= 0.f ? v0 : 0.1f * v0;
                v1 = v1 >= 0.f ? v1 : 0.1f * v1;
                v2 = v2 >= 0.f ? v2 : 0.1f * v2;
                v3 = v3 >= 0.f ? v3 : 0.1f * v3;
            }
            ushort4 uv;
            uv.x = f2bf(v0); uv.y = f2bf(v1);
            uv.z = f2bf(v2); uv.w = f2bf(v3);
            *reinterpret_cast<ushort4*>(&outb[rowoff + col0]) = uv;
        }
    }
}

// ---------------------------------------------------------------------------
// FUSED qkv-GEMM + attention. One block per (b,h), 256 threads = 4 waves.
// Phase 1: qkv[256,96] = h[b][256,256] @ Wqkv_head[96,256]^T + bias, written
//   directly into LDS layouts: Qs[256][40], Ks[256][40], Vt[32][264].
// Phase 2: MFMA attention (max-free exp2 softmax), bf16 out.
// LDS: As[256][72] (+Ws[96][72]) transient, Ps overlays As. Total 108.5 KB.
// ---------------------------------------------------------------------------
__global__ __launch_bounds__(256) void k_qkvattn(
    const ushort* __restrict__ hbuf, const ushort* __restrict__ Wqkv,
    const float* __restrict__ bias, ushort* __restrict__ o) {
    __shared__ __align__(16) ushort smem[54272];
    ushort* As = smem;                    // [256][72] = 18432
    ushort* Ws = smem + 18432;            // [96][72]  = 6912
    ushort (*Ps)[64][40] = (ushort(*)[64][40])smem;  // overlay on As
    ushort (*Qs)[40] = (ushort(*)[40])(smem + 25344);  // [256][40]
    ushort (*Ks)[40] = (ushort(*)[40])(smem + 35584);  // [256][40]
    ushort (*Vt)[264] = (ushort(*)[264])(smem + 45824); // [32][264]

    const int hd = blockIdx.x, b = blockIdx.y;
    const int tid = threadIdx.x;
    const int w = tid >> 6, lane = tid & 63;
    const int fr = lane & 15, fq = lane >> 4;

    // ---- phase 1: qkv GEMM ----
    const ushort* aS = hbuf + (size_t)b * 65536 + (size_t)tid * 256;
    int wgrow = 0;
    if (tid < 192) {
        const int r96 = tid >> 1;
        wgrow = r96 < 32 ? hd * 32 + r96
              : (r96 < 64 ? 256 + hd * 32 + (r96 - 32)
                          : 512 + hd * 32 + (r96 - 64));
    }

    f4_t acc[4][6];
#pragma unroll
    for (int i = 0; i < 4; ++i)
#pragma unroll
        for (int j = 0; j < 6; ++j) acc[i][j] = (f4_t)0.f;

    for (int k0 = 0; k0 < 256; k0 += 64) {
        {
            const bfrag* ap = reinterpret_cast<const bfrag*>(aS + k0);
            bfrag a0 = ap[0], a1 = ap[1], a2 = ap[2], a3 = ap[3];
            bfrag a4 = ap[4], a5 = ap[5], a6 = ap[6], a7 = ap[7];
            bfrag* ad = reinterpret_cast<bfrag*>(&As[tid * 72]);
            ad[0] = a0; ad[1] = a1; ad[2] = a2; ad[3] = a3;
            ad[4] = a4; ad[5] = a5; ad[6] = a6; ad[7] = a7;
            if (tid < 192) {
                const int r96 = tid >> 1, hf = (tid & 1) * 32;
                const bfrag* wp = reinterpret_cast<const bfrag*>(
                    Wqkv + (size_t)wgrow * 256 + k0 + hf);
                bfrag w0 = wp[0], w1 = wp[1], w2 = wp[2], w3 = wp[3];
                bfrag* wd = reinterpret_cast<bfrag*>(&Ws[r96 * 72 + hf]);
                wd[0] = w0; wd[1] = w1; wd[2] = w2; wd[3] = w3;
            }
        }
        __syncthreads();
#pragma unroll
        for (int ks = 0; ks < 2; ++ks) {
            const int kb = ks * 32 + fq * 8;
            bfrag af[4], bf[6];
#pragma unroll
            for (int fm = 0; fm < 4; ++fm)
                af[fm] = *reinterpret_cast<const bfrag*>(
                    &As[(w * 64 + fm * 16 + fr) * 72 + kb]);
#pragma unroll
            for (int cf = 0; cf < 6; ++cf)
                bf[cf] = *reinterpret_cast<const bfrag*>(
                    &Ws[(cf * 16 + fr) * 72 + kb]);
#pragma unroll
            for (int fm = 0; fm < 4; ++fm)
#pragma unroll
                for (int cf = 0; cf < 6; ++cf)
                    acc[fm][cf] = __builtin_amdgcn_mfma_f32_16x16x32_bf16(
                        bf[cf], af[fm], acc[fm][cf], 0, 0, 0);
        }
        __syncthreads();
    }

    // epilogue: bias, write q/k/v into attention LDS layouts
#pragma unroll
    for (int cf = 0; cf < 6; ++cf) {
        const int c0 = cf * 16 + fq * 4;  // local col 0..95
        const int cl = c0 & 31;           // col within section
        const int gbase = (cf < 2) ? hd * 32 + cl
                        : (cf < 4) ? 256 + hd * 32 + cl
                                   : 512 + hd * 32 + cl;
        const float4 bv = *reinterpret_cast<const float4*>(&bias[gbase]);
#pragma unroll
        for (int fm = 0; fm < 4; ++fm) {
            const int row = w * 64 + fm * 16 + fr;
            float v0 = acc[fm][cf][0] + bv.x;
            float v1 = acc[fm][cf][1] + bv.y;
            float v2 = acc[fm][cf][2] + bv.z;
            float v3 = acc[fm][cf][3] + bv.w;
            if (cf < 2) {
                ushort4 uv;
                uv.x = f2bf(v0); uv.y = f2bf(v1);
                uv.z = f2bf(v2); uv.w = f2bf(v3);
                *reinterpret_cast<ushort4*>(&Qs[row][cl]) = uv;
            } else if (cf < 4) {
                ushort4 uv;
                uv.x = f2bf(v0); uv.y = f2bf(v1);
                uv.z = f2bf(v2); uv.w = f2bf(v3);
                *reinterpret_cast<ushort4*>(&Ks[row][cl]) = uv;
            } else {
                Vt[cl + 0][row] = f2bf(v0);
                Vt[cl + 1][row] = f2bf(v1);
                Vt[cl + 2][row] = f2bf(v2);
                Vt[cl + 3][row] = f2bf(v3);
            }
        }
    }
    __syncthreads();

    // ---- phase 2: attention ----
    const int q0 = w * 64;
    bfrag qf[4];
#pragma unroll
    for (int fm = 0; fm < 4; ++fm)
        qf[fm] = *reinterpret_cast<const bfrag*>(&Qs[q0 + fm * 16 + fr][fq * 8]);

    f4_t oacc[4][2];
    float rs[4][4];
#pragma unroll
    for (int fm = 0; fm < 4; ++fm) {
        oacc[fm][0] = (f4_t)0.f;
        oacc[fm][1] = (f4_t)0.f;
#pragma unroll
        for (int j = 0; j < 4; ++j) rs[fm][j] = 0.f;
    }
    const f4_t zero4 = (f4_t)0.f;
    const float qsl = 0.17677669529663687f * 1.4426950408889634f;

    for (int kt = 0; kt < 8; ++kt) {
        bfrag kf0 = *reinterpret_cast<const bfrag*>(&Ks[kt * 32 + fr][fq * 8]);
        bfrag kf1 = *reinterpret_cast<const bfrag*>(&Ks[kt * 32 + 16 + fr][fq * 8]);
        f4_t s0[4], s1[4];
#pragma unroll
        for (int fm = 0; fm < 4; ++fm) {
            s0[fm] = __builtin_amdgcn_mfma_f32_16x16x32_bf16(qf[fm], kf0, zero4, 0, 0, 0);
            s1[fm] = __builtin_amdgcn_mfma_f32_16x16x32_bf16(qf[fm], kf1, zero4, 0, 0, 0);
        }
#pragma unroll
        for (int fm = 0; fm < 4; ++fm) {
#pragma unroll
            for (int j = 0; j < 4; ++j) {
                const int row = fm * 16 + fq * 4 + j;
                ushort u0 = f2bf(exp2f(s0[fm][j] * qsl));
                ushort u1 = f2bf(exp2f(s1[fm][j] * qsl));
                Ps[w][row][fr] = u0;
                Ps[w][row][16 + fr] = u1;
                rs[fm][j] += bf2f(u0) + bf2f(u1);
            }
        }
        bfrag vf0 = *reinterpret_cast<const bfrag*>(&Vt[fr][kt * 32 + fq * 8]);
        bfrag vf1 = *reinterpret_cast<const bfrag*>(&Vt[16 + fr][kt * 32 + fq * 8]);
        bfrag pf[4];
#pragma unroll
        for (int fm = 0; fm < 4; ++fm)
            pf[fm] = *reinterpret_cast<const bfrag*>(&Ps[w][fm * 16 + fr][fq * 8]);
#pragma unroll
        for (int fm = 0; fm < 4; ++fm) {
            oacc[fm][0] = __builtin_amdgcn_mfma_f32_16x16x32_bf16(pf[fm], vf0, oacc[fm][0], 0, 0, 0);
            oacc[fm][1] = __builtin_amdgcn_mfma_f32_16x16x32_bf16(pf[fm], vf1, oacc[fm][1], 0, 0, 0);
        }
    }

#pragma unroll
    for (int fm = 0; fm < 4; ++fm)
#pragma unroll
        for (int j = 0; j < 4; ++j) {
            float r = rs[fm][j];
            r += __shfl_xor(r, 1);
            r += __shfl_xor(r, 2);
            r += __shfl_xor(r, 4);
            r += __shfl_xor(r, 8);
            rs[fm][j] = 1.f / r;
        }
    ushort* ob = o + (size_t)b * 65536 + hd * 32;
#pragma unroll
    for (int fm = 0; fm < 4; ++fm) {
        const int qrow = q0 + fm * 16 + fq * 4;
#pragma unroll
        for (int j = 0; j < 4; ++j) {
            const float inv = rs[fm][j];
            ob[(size_t)(qrow + j) * 256 + fr] = f2bf(oacc[fm][0][j] * inv);
            ob[(size_t)(qrow + j) * 256 + 16 + fr] = f2bf(oacc[fm][1][j] * inv);
        }
    }
}

// ---------------------------------------------------------------------------
// Transpose+convert for message passing.
// ---------------------------------------------------------------------------
__global__ __launch_bounds__(256) void k_xpose_bmm(
    const float* __restrict__ x, const float* __restrict__ nv,
    const float* __restrict__ ev, ushort* __restrict__ At,
    ushort* __restrict__ Xt) {
    const int b = blockIdx.z;
    const int k0 = blockIdx.x * 64, i0 = blockIdx.y * 64;
    __shared__ float TA[64][65];
    __shared__ float TX[64][65];
    const size_t bb = (size_t)b * 65536;
    const int tid = threadIdx.x;
    const int lr = tid >> 4, lc = (tid & 15) * 4;
#pragma unroll
    for (int l = 0; l < 4; ++l) {
        const int row = lr + l * 16;
        const size_t gidx = bb + (size_t)(k0 + row) * 256 + i0 + lc;
        float4 n4 = *reinterpret_cast<const float4*>(nv + gidx);
        float4 e4 = *reinterpret_cast<const float4*>(ev + gidx);
        float4 x4 = *reinterpret_cast<const float4*>(x + gidx);
        TA[row][lc] = 0.5f * (n4.x + e4.x);
        TA[row][lc + 1] = 0.5f * (n4.y + e4.y);
        TA[row][lc + 2] = 0.5f * (n4.z + e4.z);
        TA[row][lc + 3] = 0.5f * (n4.w + e4.w);
        TX[row][lc] = x4.x;
        TX[row][lc + 1] = x4.y;
        TX[row][lc + 2] = x4.z;
        TX[row][lc + 3] = x4.w;
    }
    __syncthreads();
    const int i = tid & 63, kk = (tid >> 6) * 16;
    bfrag a0, a1, x0, x1;
#pragma unroll
    for (int e = 0; e < 8; ++e) {
        a0[e] = (short)f2bf(TA[kk + e][i]);
        a1[e] = (short)f2bf(TA[kk + 8 + e][i]);
        x0[e] = (short)f2bf(TX[kk + e][i]);
        x1[e] = (short)f2bf(TX[kk + 8 + e][i]);
    }
    const size_t o = bb + (size_t)(i0 + i) * 256 + k0 + kk;
    *reinterpret_cast<bfrag*>(At + o) = a0;
    *reinterpret_cast<bfrag*>(At + o + 8) = a1;
    *reinterpret_cast<bfrag*>(Xt + o) = x0;
    *reinterpret_cast<bfrag*>(Xt + o + 8) = x1;
}

// ---------------------------------------------------------------------------
// Fused Pearson prep.
// ---------------------------------------------------------------------------
__global__ __launch_bounds__(256) void k_pstats(const ushort* __restrict__ y,
                                                ushort* __restrict__ cnT) {
    const int b = blockIdx.y, r0 = blockIdx.x * 64;
    __shared__ __align__(16) ushort T[256][72];
    __shared__ float sred[4][64];
    __shared__ float qred[4][64];
    __shared__ float mstat[64];
    __shared__ float istat[64];
    const int tid = threadIdx.x;
    {
        const bfrag* yv = reinterpret_cast<const bfrag*>(
            y + (size_t)b * 65536 + (size_t)tid * 256 + r0);
#pragma unroll
        for (int i = 0; i < 8; ++i)
            *reinterpret_cast<bfrag*>(&T[tid][i * 8]) = yv[i];
    }
    __syncthreads();
    const int rl = tid & 63, tc = tid >> 6;
    {
        float s = 0.f, q = 0.f;
        for (int t = 0; t < 64; ++t) {
            float v = bf2f(T[tc * 64 + t][rl]);
            s += v;
            q += v * v;
        }
        sred[tc][rl] = s;
        qred[tc][rl] = q;
    }
    __syncthreads();
    if (tid < 64) {
        const float S = sred[0][tid] + sred[1][tid] + sred[2][tid] + sred[3][tid];
        const float Q = qred[0][tid] + qred[1][tid] + qred[2][tid] + qred[3][tid];
        const float mean = S * (1.f / 256.f);
        const float var = (Q - S * mean) * (1.f / 255.f);
        const float stdv = sqrtf(fmaxf(var, 0.f));
        mstat[tid] = mean;
        istat[tid] = 1.f / (stdv + 1e-8f);
    }
    __syncthreads();
    const float mean = mstat[rl], inv = istat[rl];
    ushort* dst = cnT + (size_t)b * 65536 + (size_t)(r0 + rl) * 256 + tc * 64;
#pragma unroll
    for (int i = 0; i < 8; ++i) {
        bfrag c;
#pragma unroll
        for (int e = 0; e < 8; ++e)
            c[e] = (short)f2bf((bf2f(T[tc * 64 + i * 8 + e][rl]) - mean) * inv);
        reinterpret_cast<bfrag*>(dst)[i] = c;
    }
}

// ---------------------------------------------------------------------------
// Fused mean-pool + both MLP heads. One block per b, 512 threads.
// ---------------------------------------------------------------------------
__global__ __launch_bounds__(512) void k_poolhead(
    const ushort* __restrict__ h,
    const float* __restrict__ mw1, const float* __restrict__ mb1,
    const float* __restrict__ mg, const float* __restrict__ mbt,
    const float* __restrict__ mw2, const float* __restrict__ mb2,
    const float* __restrict__ lw1, const float* __restrict__ lb1,
    const float* __restrict__ lg, const float* __restrict__ lbt,
    const float* __restrict__ lw2, const float* __restrict__ lb2,
    float* __restrict__ outp) {
    const int b = blockIdx.x, tid = threadIdx.x;
    __shared__ float pp[2][256];
    __shared__ float pooled[256];
    __shared__ float rS[4], rQ[4];
    __shared__ float t1[2][128];

    // pool: 2-way t-split
    {
        const int c = tid & 255, tc = tid >> 8;
        const ushort* hb = h + (size_t)b * 65536 + (size_t)tc * 128 * 256 + c;
        float s = 0.f;
        for (int t = 0; t < 128; ++t) s += bf2f(hb[(size_t)t * 256]);
        pp[tc][c] = s;
    }
    __syncthreads();
    if (tid < 256) pooled[tid] = (pp[0][tid] + pp[1][tid]) * (1.f / 256.f);
    __syncthreads();

    // layer 1: 2 heads x 128 units
    float a = 0.f;
    if (tid < 256) {
        const int hd = tid >> 7, u = tid & 127;
        const float* w1 = hd ? lw1 : mw1;
        const float* b1 = hd ? lb1 : mb1;
        a = b1[u];
        const float4* w1v = reinterpret_cast<const float4*>(w1 + (size_t)u * 256);
#pragma unroll 4
        for (int k4 = 0; k4 < 64; ++k4) {
            float4 wv = w1v[k4];
            float4 p = *reinterpret_cast<const float4*>(&pooled[k4 * 4]);
            a = dot4(p, wv, a);
        }
        float s = a, q = a * a;
#pragma unroll
        for (int m = 1; m < 64; m <<= 1) {
            s += __shfl_xor(s, m);
            q += __shfl_xor(q, m);
        }
        if ((tid & 63) == 0) { rS[tid >> 6] = s; rQ[tid >> 6] = q; }
    }
    __syncthreads();
    if (tid < 256) {
        const int hd = tid >> 7, u = tid & 127;
        const float* g = hd ? lg : mg;
        const float* bt = hd ? lbt : mbt;
        const float S = rS[hd * 2] + rS[hd * 2 + 1];
        const float Q = rQ[hd * 2] + rQ[hd * 2 + 1];
        const float mean = S * (1.f / 128.f);
        const float var = Q * (1.f / 128.f) - mean * mean;
        const float rstd = rsqrtf(fmaxf(var, 0.f) + 1e-5f);
        float v = (a - mean) * rstd * g[u] + bt[u];
        v = v >= 0.f ? v : 0.1f * v;
        t1[hd][u] = v;
    }
    __syncthreads();
    if (tid < 128) {
        const int hd = tid >> 6, ou = tid & 63;
        const float* w2 = hd ? lw2 : mw2;
        const float* b2 = hd ? lb2 : mb2;
        float o = b2[ou];
        const float* w2r = w2 + (size_t)ou * 128;
#pragma unroll 4
        for (int c = 0; c < 128; ++c) o = fmaf(t1[hd][c], w2r[c], o);
        outp[hd * 4096 + b * 64 + ou] = o;
    }
}

// ---------------------------------------------------------------------------
extern "C" void kernel_launch(void* const* d_in, const int* in_sizes, int n_in,
                              void* d_out, int out_size, void* d_ws, size_t ws_size,
                              hipStream_t stream) {
    const float* x = (const float*)d_in[0];
    const float* nv = (const float*)d_in[1];
    const float* ev = (const float*)d_in[2];
    const float* fp_w = (const float*)d_in[3];
    const float* fp_b = (const float*)d_in[4];
    const float* fp_g = (const float*)d_in[5];
    const float* fp_beta = (const float*)d_in[6];
    const float* qkv_w = (const float*)d_in[7];
    const float* qkv_b = (const float*)d_in[8];
    const float* aow = (const float*)d_in[9];
    const float* aob = (const float*)d_in[10];
    const float* ln1g = (const float*)d_in[11];
    const float* ln1b = (const float*)d_in[12];
    const float* f1w = (const float*)d_in[13];
    const float* f1b = (const float*)d_in[14];
    const float* f2w = (const float*)d_in[15];
    const float* f2b = (const float*)d_in[16];
    const float* ln2g = (const float*)d_in[17];
    const float* ln2b = (const float*)d_in[18];
    const float* outw = (const float*)d_in[19];
    const float* outb = (const float*)d_in[20];
    const float* muw1 = (const float*)d_in[21];
    const float* mub1 = (const float*)d_in[22];
    const float* mug = (const float*)d_in[23];
    const float* mubt = (const float*)d_in[24];
    const float* muw2 = (const float*)d_in[25];
    const float* mub2 = (const float*)d_in[26];
    const float* lvw1 = (const float*)d_in[27];
    const float* lvb1 = (const float*)d_in[28];
    const float* lvg = (const float*)d_in[29];
    const float* lvbt = (const float*)d_in[30];
    const float* lvw2 = (const float*)d_in[31];
    const float* lvb2 = (const float*)d_in[32];

    float* out = (float*)d_out;
    float* ws = (float*)d_ws;

    // bf16 regions (ushort elements)
    ushort* ub = (ushort*)ws;
    ushort* wh_bf = ub;                    // [16384,256]
    ushort* At = ub + 4194304;             // [64,256,256]
    ushort* Xt = ub + 8388608;             // [64,256,256]
    ushort* o_bf = ub + 16777216;          // [16384,256]; h0_bf alias
    ushort* h0_bf = o_bf;
    ushort* f1_bf = ub + 20971520;         // [16384,512]; cnT alias
    ushort* cnT = f1_bf;
    ushort* y_bf = ub + 29360128;          // [16384,256]
    ushort* wbf = ub + 33554432;           // weights, 1179648

    // 0. weights -> bf16
    k_cvt<<<576, 256, 0, stream>>>(fp_w, qkv_w, aow, f1w, f2w, outw, wbf);

    // 1. message passing: transpose inputs, batched MFMA -> h0_bf
    k_xpose_bmm<<<dim3(4, 4, BB), 256, 0, stream>>>(x, nv, ev, At, Xt);
    k_mm<0, false, true><<<dim3(4, 2, BB), 256, 0, stream>>>(
        At, Xt, nullptr, nullptr, h0_bf, 256, 256, 65536, 65536, 65536);

    // 2. feature proj + LN + leaky (fused) -> wh_bf
    k_mmln<1, false><<<512, 256, 0, stream>>>(
        h0_bf, wbf, fp_b, nullptr, fp_g, fp_beta, wh_bf, 256);

    // 3. transformer layers (qkv+attention fused)
    for (int l = 0; l < NLAYER; ++l) {
        k_qkvattn<<<dim3(8, BB), 256, 0, stream>>>(
            wh_bf, wbf + 65536 + (size_t)l * 196608, qkv_b + l * 768, o_bf);
        k_mmln<0, true><<<512, 256, 0, stream>>>(
            o_bf, wbf + 458752 + (size_t)l * 65536, aob + l * 256,
            wh_bf, ln1g + l * 256, ln1b + l * 256, wh_bf, 256);
        k_mm<2, false, true><<<dim3(256, 4, 1), 256, 0, stream>>>(
            wh_bf, wbf + 589824 + (size_t)l * 131072, f1b + l * 512,
            nullptr, f1_bf, 256, 512, 0, 0, 0);
        k_mmln<0, true><<<512, 256, 0, stream>>>(
            f1_bf, wbf + 851968 + (size_t)l * 131072, f2b + l * 256,
            wh_bf, ln2g + l * 256, ln2b + l * 256, wh_bf, 512);
    }

    // 4. y = h @ out_w^T + out_b -> y_bf
    k_mm<0, false, true><<<dim3(256, 2, 1), 256, 0, stream>>>(
        wh_bf, wbf + 1114112, outb, nullptr, y_bf, 256, 256, 0, 0, 0);

    // 5. Pearson: fused stats+transpose+normalize, then batched MFMA SYRK
    k_pstats<<<dim3(4, BB), 256, 0, stream>>>(y_bf, cnT);
    k_mm<3, true, false><<<dim3(4, 2, BB), 256, 0, stream>>>(
        cnT, cnT, nullptr, out + 8192, nullptr, 256, 256, 65536, 65536, 65536);

    // 6. fused pool + heads
    k_poolhead<<<BB, 512, 0, stream>>>(
        wh_bf, muw1, mub1, mug, mubt, muw2, mub2,
        lvw1, lvb1, lvg, lvbt, lvw2, lvb2, out);
}

// Round 9
// 239.118 us; speedup vs baseline: 1.0926x; 1.0926x over previous
//
#include <hip/hip_runtime.h>
#include <hip/hip_bf16.h>
#include <math.h>

#define BB 64
#define NLAYER 2

typedef __attribute__((ext_vector_type(8))) short bfrag;
typedef __attribute__((ext_vector_type(4))) float f4_t;

__device__ __forceinline__ float dot4(float4 a, float4 b, float acc) {
    acc = fmaf(a.x, b.x, acc);
    acc = fmaf(a.y, b.y, acc);
    acc = fmaf(a.z, b.z, acc);
    acc = fmaf(a.w, b.w, acc);
    return acc;
}

// fp32 -> bf16 round-to-nearest-even
__device__ __forceinline__ ushort f2bf(float f) {
    uint32_t u = __float_as_uint(f);
    uint32_t r = (u + 0x7FFFu + ((u >> 16) & 1u)) >> 16;
    return (ushort)r;
}
__device__ __forceinline__ float bf2f(ushort u) {
    return __uint_as_float(((uint32_t)u) << 16);
}

// ---------------------------------------------------------------------------
// Weight conversion fp32 -> bf16 into one ws region.
// offsets (elements): fp:0, qkv:65536, aow:458752, f1:589824, f2:851968,
// out:1114112; total 1179648. 2048 elems/block, 576 blocks.
// ---------------------------------------------------------------------------
__global__ __launch_bounds__(256) void k_cvt(
    const float* __restrict__ fp_w, const float* __restrict__ qkv_w,
    const float* __restrict__ aow, const float* __restrict__ f1w,
    const float* __restrict__ f2w, const float* __restrict__ outw,
    ushort* __restrict__ dst) {
    const int g = blockIdx.x;
    const size_t idx = (size_t)g * 2048 + threadIdx.x * 8;
    const float* src;
    size_t base;
    if (g < 32)       { src = fp_w;  base = 0; }
    else if (g < 224) { src = qkv_w; base = 65536; }
    else if (g < 288) { src = aow;   base = 458752; }
    else if (g < 416) { src = f1w;   base = 589824; }
    else if (g < 544) { src = f2w;   base = 851968; }
    else              { src = outw;  base = 1114112; }
    const float4* s4 = reinterpret_cast<const float4*>(src + (idx - base));
    float4 a = s4[0], b = s4[1];
    bfrag o;
    o[0] = (short)f2bf(a.x); o[1] = (short)f2bf(a.y);
    o[2] = (short)f2bf(a.z); o[3] = (short)f2bf(a.w);
    o[4] = (short)f2bf(b.x); o[5] = (short)f2bf(b.y);
    o[6] = (short)f2bf(b.z); o[7] = (short)f2bf(b.w);
    *reinterpret_cast<bfrag*>(dst + idx) = o;
}

// ---------------------------------------------------------------------------
// bf16 MFMA GEMM, BM=64 BN=128, register prefetch, swapped mfma.
// EPI: 0 none, 2 relu. grid (M/64, N/128, nbatch).
// ---------------------------------------------------------------------------
template <int EPI, bool WF32, bool WBF>
__global__ __launch_bounds__(256) void k_mm(
    const ushort* __restrict__ A, const ushort* __restrict__ B,
    const float* __restrict__ bias, float* __restrict__ C,
    ushort* __restrict__ Cb, int K, int N,
    size_t aStr, size_t bStr, size_t cStr) {
    __shared__ __align__(16) ushort As[64 * 72];
    __shared__ __align__(16) ushort Bs[128 * 72];
    const int tid = threadIdx.x;
    const int m0 = blockIdx.x * 64, n0 = blockIdx.y * 128;
    const size_t z = blockIdx.z;
    const int w = tid >> 6, lane = tid & 63;
    const int wm = w >> 1, wn = w & 1;
    const int fr = lane & 15, fq = lane >> 4;

    const int arow = tid >> 2, akc = (tid & 3) * 16;
    const ushort* aS = A + z * aStr + (size_t)(m0 + arow) * K + akc;
    ushort* aD = &As[arow * 72 + akc];
    const int brow = tid >> 1, bkc = (tid & 1) * 32;
    const ushort* bS = B + z * bStr + (size_t)(n0 + brow) * K + bkc;
    ushort* bD = &Bs[brow * 72 + bkc];

    f4_t acc[2][4];
#pragma unroll
    for (int i = 0; i < 2; ++i)
#pragma unroll
        for (int j = 0; j < 4; ++j) acc[i][j] = (f4_t)0.f;

    bfrag ra0, ra1, rb0, rb1, rb2, rb3;
    {
        const bfrag* ap = reinterpret_cast<const bfrag*>(aS);
        ra0 = ap[0]; ra1 = ap[1];
        const bfrag* bp = reinterpret_cast<const bfrag*>(bS);
        rb0 = bp[0]; rb1 = bp[1]; rb2 = bp[2]; rb3 = bp[3];
    }

    for (int k0 = 0; k0 < K; k0 += 64) {
        reinterpret_cast<bfrag*>(aD)[0] = ra0;
        reinterpret_cast<bfrag*>(aD)[1] = ra1;
        reinterpret_cast<bfrag*>(bD)[0] = rb0;
        reinterpret_cast<bfrag*>(bD)[1] = rb1;
        reinterpret_cast<bfrag*>(bD)[2] = rb2;
        reinterpret_cast<bfrag*>(bD)[3] = rb3;
        __syncthreads();
        if (k0 + 64 < K) {
            const bfrag* ap = reinterpret_cast<const bfrag*>(aS + k0 + 64);
            ra0 = ap[0]; ra1 = ap[1];
            const bfrag* bp = reinterpret_cast<const bfrag*>(bS + k0 + 64);
            rb0 = bp[0]; rb1 = bp[1]; rb2 = bp[2]; rb3 = bp[3];
        }
#pragma unroll
        for (int ks = 0; ks < 2; ++ks) {
            const int kb = ks * 32 + fq * 8;
            bfrag af[2], bf[4];
#pragma unroll
            for (int fm = 0; fm < 2; ++fm)
                af[fm] = *reinterpret_cast<const bfrag*>(
                    &As[(wm * 32 + fm * 16 + fr) * 72 + kb]);
#pragma unroll
            for (int fn = 0; fn < 4; ++fn)
                bf[fn] = *reinterpret_cast<const bfrag*>(
                    &Bs[(wn * 64 + fn * 16 + fr) * 72 + kb]);
#pragma unroll
            for (int fm = 0; fm < 2; ++fm)
#pragma unroll
                for (int fn = 0; fn < 4; ++fn)
                    acc[fm][fn] = __builtin_amdgcn_mfma_f32_16x16x32_bf16(
                        bf[fn], af[fm], acc[fm][fn], 0, 0, 0);
        }
        __syncthreads();
    }

#pragma unroll
    for (int fn = 0; fn < 4; ++fn) {
        const int col0 = n0 + wn * 64 + fn * 16 + fq * 4;
        float4 bv = make_float4(0.f, 0.f, 0.f, 0.f);
        if (bias != nullptr)
            bv = *reinterpret_cast<const float4*>(&bias[col0]);
#pragma unroll
        for (int fm = 0; fm < 2; ++fm) {
            const int row = m0 + wm * 32 + fm * 16 + fr;
            float v0 = acc[fm][fn][0] + bv.x;
            float v1 = acc[fm][fn][1] + bv.y;
            float v2 = acc[fm][fn][2] + bv.z;
            float v3 = acc[fm][fn][3] + bv.w;
            if (EPI == 2) {
                v0 = fmaxf(v0, 0.f); v1 = fmaxf(v1, 0.f);
                v2 = fmaxf(v2, 0.f); v3 = fmaxf(v3, 0.f);
            }
            const size_t o = cStr * z + (size_t)row * N + col0;
            if (WF32) {
                float4 fv = {v0, v1, v2, v3};
                *reinterpret_cast<float4*>(&C[o]) = fv;
            }
            if (WBF) {
                ushort4 uv;
                uv.x = f2bf(v0); uv.y = f2bf(v1);
                uv.z = f2bf(v2); uv.w = f2bf(v3);
                *reinterpret_cast<ushort4*>(&Cb[o]) = uv;
            }
        }
    }
}

// ---------------------------------------------------------------------------
// qkv GEMM: same core as k_mm (K=256, N=768, M=16384), epilogue writes
// head-blocked layouts: qb/kb [b,h,t,32], vtb (V transposed) [b,h,32,t].
// grid (256, 6).
// ---------------------------------------------------------------------------
__global__ __launch_bounds__(256) void k_mmqkv(
    const ushort* __restrict__ A, const ushort* __restrict__ B,
    const float* __restrict__ bias, ushort* __restrict__ qb,
    ushort* __restrict__ kbuf, ushort* __restrict__ vtb) {
    __shared__ __align__(16) ushort As[64 * 72];
    __shared__ __align__(16) ushort Bs[128 * 72];
    const int tid = threadIdx.x;
    const int m0 = blockIdx.x * 64, n0 = blockIdx.y * 128;
    const int w = tid >> 6, lane = tid & 63;
    const int wm = w >> 1, wn = w & 1;
    const int fr = lane & 15, fq = lane >> 4;
    const int K = 256;

    const int arow = tid >> 2, akc = (tid & 3) * 16;
    const ushort* aS = A + (size_t)(m0 + arow) * K + akc;
    ushort* aD = &As[arow * 72 + akc];
    const int brow = tid >> 1, bkc = (tid & 1) * 32;
    const ushort* bS = B + (size_t)(n0 + brow) * K + bkc;
    ushort* bD = &Bs[brow * 72 + bkc];

    f4_t acc[2][4];
#pragma unroll
    for (int i = 0; i < 2; ++i)
#pragma unroll
        for (int j = 0; j < 4; ++j) acc[i][j] = (f4_t)0.f;

    bfrag ra0, ra1, rb0, rb1, rb2, rb3;
    {
        const bfrag* ap = reinterpret_cast<const bfrag*>(aS);
        ra0 = ap[0]; ra1 = ap[1];
        const bfrag* bp = reinterpret_cast<const bfrag*>(bS);
        rb0 = bp[0]; rb1 = bp[1]; rb2 = bp[2]; rb3 = bp[3];
    }

    for (int k0 = 0; k0 < K; k0 += 64) {
        reinterpret_cast<bfrag*>(aD)[0] = ra0;
        reinterpret_cast<bfrag*>(aD)[1] = ra1;
        reinterpret_cast<bfrag*>(bD)[0] = rb0;
        reinterpret_cast<bfrag*>(bD)[1] = rb1;
        reinterpret_cast<bfrag*>(bD)[2] = rb2;
        reinterpret_cast<bfrag*>(bD)[3] = rb3;
        __syncthreads();
        if (k0 + 64 < K) {
            const bfrag* ap = reinterpret_cast<const bfrag*>(aS + k0 + 64);
            ra0 = ap[0]; ra1 = ap[1];
            const bfrag* bp = reinterpret_cast<const bfrag*>(bS + k0 + 64);
            rb0 = bp[0]; rb1 = bp[1]; rb2 = bp[2]; rb3 = bp[3];
        }
#pragma unroll
        for (int ks = 0; ks < 2; ++ks) {
            const int kb = ks * 32 + fq * 8;
            bfrag af[2], bf[4];
#pragma unroll
            for (int fm = 0; fm < 2; ++fm)
                af[fm] = *reinterpret_cast<const bfrag*>(
                    &As[(wm * 32 + fm * 16 + fr) * 72 + kb]);
#pragma unroll
            for (int fn = 0; fn < 4; ++fn)
                bf[fn] = *reinterpret_cast<const bfrag*>(
                    &Bs[(wn * 64 + fn * 16 + fr) * 72 + kb]);
#pragma unroll
            for (int fm = 0; fm < 2; ++fm)
#pragma unroll
                for (int fn = 0; fn < 4; ++fn)
                    acc[fm][fn] = __builtin_amdgcn_mfma_f32_16x16x32_bf16(
                        bf[fn], af[fm], acc[fm][fn], 0, 0, 0);
        }
        __syncthreads();
    }

    const int sec = n0 >> 8;  // 0=q, 1=k, 2=v (block-uniform)
#pragma unroll
    for (int fn = 0; fn < 4; ++fn) {
        const int col0 = n0 + wn * 64 + fn * 16 + fq * 4;
        const int hd = (col0 >> 5) & 7, dq = col0 & 31;
        const float4 bv = *reinterpret_cast<const float4*>(&bias[col0]);
#pragma unroll
        for (int fm = 0; fm < 2; ++fm) {
            const int row = m0 + wm * 32 + fm * 16 + fr;
            const int b = row >> 8, t = row & 255;
            const size_t bh = (size_t)b * 8 + hd;
            float v0 = acc[fm][fn][0] + bv.x;
            float v1 = acc[fm][fn][1] + bv.y;
            float v2 = acc[fm][fn][2] + bv.z;
            float v3 = acc[fm][fn][3] + bv.w;
            if (sec < 2) {
                ushort4 uv;
                uv.x = f2bf(v0); uv.y = f2bf(v1);
                uv.z = f2bf(v2); uv.w = f2bf(v3);
                ushort* dst = (sec == 0 ? qb : kbuf) + (bh * 256 + t) * 32 + dq;
                *reinterpret_cast<ushort4*>(dst) = uv;
            } else {
                ushort* dst = vtb + (bh * 32 + dq) * 256 + t;
                dst[0] = f2bf(v0);
                dst[256] = f2bf(v1);
                dst[512] = f2bf(v2);
                dst[768] = f2bf(v3);
            }
        }
    }
}

// ---------------------------------------------------------------------------
// Fused GEMM + bias (+bf16 residual) + LayerNorm(256) (+leaky) -> bf16 only.
// BM=32, BN=256=N, 256 threads = 4 waves; + register prefetch.
// ---------------------------------------------------------------------------
template <int ACT, bool RES>
__global__ __launch_bounds__(256) void k_mmln(
    const ushort* __restrict__ A, const ushort* __restrict__ W,
    const float* __restrict__ bias, const ushort* __restrict__ res,
    const float* __restrict__ g, const float* __restrict__ bt,
    ushort* __restrict__ outb, int K) {
    __shared__ __align__(16) ushort As[32 * 72];
    __shared__ __align__(16) ushort Bs[256 * 72];
    __shared__ float redS[32][4];
    __shared__ float redQ[32][4];
    const int tid = threadIdx.x;
    const int m0 = blockIdx.x * 32;
    const int w = tid >> 6, lane = tid & 63;
    const int fr = lane & 15, fq = lane >> 4;

    const int arow = tid >> 3, akc = (tid & 7) * 8;
    const ushort* aS = A + (size_t)(m0 + arow) * K + akc;
    ushort* aD = &As[arow * 72 + akc];
    const int brow = tid >> 1, bkc = (tid & 1) * 32;
    const ushort* bS0 = W + (size_t)brow * K + bkc;
    const ushort* bS1 = W + (size_t)(brow + 128) * K + bkc;
    ushort* bD0 = &Bs[brow * 72 + bkc];
    ushort* bD1 = &Bs[(brow + 128) * 72 + bkc];

    f4_t acc[2][4];
#pragma unroll
    for (int i = 0; i < 2; ++i)
#pragma unroll
        for (int j = 0; j < 4; ++j) acc[i][j] = (f4_t)0.f;

    bfrag ra, rb0, rb1, rb2, rb3, rc0, rc1, rc2, rc3;
    {
        ra = *reinterpret_cast<const bfrag*>(aS);
        const bfrag* bp0 = reinterpret_cast<const bfrag*>(bS0);
        rb0 = bp0[0]; rb1 = bp0[1]; rb2 = bp0[2]; rb3 = bp0[3];
        const bfrag* bp1 = reinterpret_cast<const bfrag*>(bS1);
        rc0 = bp1[0]; rc1 = bp1[1]; rc2 = bp1[2]; rc3 = bp1[3];
    }

    for (int k0 = 0; k0 < K; k0 += 64) {
        *reinterpret_cast<bfrag*>(aD) = ra;
        reinterpret_cast<bfrag*>(bD0)[0] = rb0;
        reinterpret_cast<bfrag*>(bD0)[1] = rb1;
        reinterpret_cast<bfrag*>(bD0)[2] = rb2;
        reinterpret_cast<bfrag*>(bD0)[3] = rb3;
        reinterpret_cast<bfrag*>(bD1)[0] = rc0;
        reinterpret_cast<bfrag*>(bD1)[1] = rc1;
        reinterpret_cast<bfrag*>(bD1)[2] = rc2;
        reinterpret_cast<bfrag*>(bD1)[3] = rc3;
        __syncthreads();
        if (k0 + 64 < K) {
            ra = *reinterpret_cast<const bfrag*>(aS + k0 + 64);
            const bfrag* bp0 = reinterpret_cast<const bfrag*>(bS0 + k0 + 64);
            rb0 = bp0[0]; rb1 = bp0[1]; rb2 = bp0[2]; rb3 = bp0[3];
            const bfrag* bp1 = reinterpret_cast<const bfrag*>(bS1 + k0 + 64);
            rc0 = bp1[0]; rc1 = bp1[1]; rc2 = bp1[2]; rc3 = bp1[3];
        }
#pragma unroll
        for (int ks = 0; ks < 2; ++ks) {
            const int kb = ks * 32 + fq * 8;
            bfrag af[2], bf[4];
#pragma unroll
            for (int fm = 0; fm < 2; ++fm)
                af[fm] = *reinterpret_cast<const bfrag*>(
                    &As[(fm * 16 + fr) * 72 + kb]);
#pragma unroll
            for (int fn = 0; fn < 4; ++fn)
                bf[fn] = *reinterpret_cast<const bfrag*>(
                    &Bs[(w * 64 + fn * 16 + fr) * 72 + kb]);
#pragma unroll
            for (int fm = 0; fm < 2; ++fm)
#pragma unroll
                for (int fn = 0; fn < 4; ++fn)
                    acc[fm][fn] = __builtin_amdgcn_mfma_f32_16x16x32_bf16(
                        bf[fn], af[fm], acc[fm][fn], 0, 0, 0);
        }
        __syncthreads();
    }

#pragma unroll
    for (int fn = 0; fn < 4; ++fn) {
        const int col0 = w * 64 + fn * 16 + fq * 4;
        const float4 bv = *reinterpret_cast<const float4*>(&bias[col0]);
#pragma unroll
        for (int fm = 0; fm < 2; ++fm) {
            const int row = fm * 16 + fr;
            float r0 = 0.f, r1 = 0.f, r2 = 0.f, r3 = 0.f;
            if (RES) {
                ushort4 r4 = *reinterpret_cast<const ushort4*>(
                    &res[(size_t)(m0 + row) * 256 + col0]);
                r0 = bf2f(r4.x); r1 = bf2f(r4.y);
                r2 = bf2f(r4.z); r3 = bf2f(r4.w);
            }
            acc[fm][fn][0] += bv.x + r0;
            acc[fm][fn][1] += bv.y + r1;
            acc[fm][fn][2] += bv.z + r2;
            acc[fm][fn][3] += bv.w + r3;
        }
    }
#pragma unroll
    for (int fm = 0; fm < 2; ++fm) {
        float s = 0.f, q = 0.f;
#pragma unroll
        for (int fn = 0; fn < 4; ++fn)
#pragma unroll
            for (int j = 0; j < 4; ++j) {
                const float v = acc[fm][fn][j];
                s += v;
                q += v * v;
            }
        s += __shfl_xor(s, 16); q += __shfl_xor(q, 16);
        s += __shfl_xor(s, 32); q += __shfl_xor(q, 32);
        if (fq == 0) {
            redS[fm * 16 + fr][w] = s;
            redQ[fm * 16 + fr][w] = q;
        }
    }
    __syncthreads();
#pragma unroll
    for (int fm = 0; fm < 2; ++fm) {
        const int row = fm * 16 + fr;
        const float S = redS[row][0] + redS[row][1] + redS[row][2] + redS[row][3];
        const float Q = redQ[row][0] + redQ[row][1] + redQ[row][2] + redQ[row][3];
        const float mean = S * (1.f / 256.f);
        const float var = Q * (1.f / 256.f) - mean * mean;
        const float rstd = rsqrtf(fmaxf(var, 0.f) + 1e-5f);
        const size_t rowoff = (size_t)(m0 + row) * 256;
#pragma unroll
        for (int fn = 0; fn < 4; ++fn) {
            const int col0 = w * 64 + fn * 16 + fq * 4;
            const float4 g4 = *reinterpret_cast<const float4*>(&g[col0]);
            const float4 b4 = *reinterpret_cast<const float4*>(&bt[col0]);
            float v0 = (acc[fm][fn][0] - mean) * rstd * g4.x + b4.x;
            float v1 = (acc[fm][fn][1] - mean) * rstd * g4.y + b4.y;
            float v2 = (acc[fm][fn][2] - mean) * rstd * g4.z + b4.z;
            float v3 = (acc[fm][fn][3] - mean) * rstd * g4.w + b4.w;
            if (ACT == 1) {
                v0 = v0 >= 0.f ? v0 : 0.1f * v0;
                v1 = v1 >= 0.f ? v1 : 0.1f * v1;
                v2 = v2 >= 0.f ? v2 : 0.1f * v2;
                v3 = v3 >= 0.f ? v3 : 0.1f * v3;
            }
            ushort4 uv;
            uv.x = f2bf(v0); uv.y = f2bf(v1);
            uv.z = f2bf(v2); uv.w = f2bf(v3);
            *reinterpret_cast<ushort4*>(&outb[rowoff + col0]) = uv;
        }
    }
}

// ---------------------------------------------------------------------------
// Attention v3: Q/K from [b,h,t,32], V^T from [b,h,32,t] — all operand
// fragments loaded DIRECTLY from global (L2-hot). LDS = P-bounce only.
// One block per (b,h), 4 waves x 64 q rows. Max-free exp2 softmax.
// ---------------------------------------------------------------------------
__global__ __launch_bounds__(256) void k_attn3(
    const ushort* __restrict__ qb, const ushort* __restrict__ kbuf,
    const ushort* __restrict__ vtb, ushort* __restrict__ o) {
    __shared__ __align__(16) ushort Ps[4][64][40];
    const int hd = blockIdx.x, b = blockIdx.y;
    const size_t bh = (size_t)b * 8 + hd;
    const int tid = threadIdx.x;
    const int w = tid >> 6, lane = tid & 63;
    const int fr = lane & 15, fq = lane >> 4;

    const ushort* qB = qb + bh * 8192;
    const ushort* kB = kbuf + bh * 8192;
    const ushort* vB = vtb + bh * 8192;

    const int q0 = w * 64;
    bfrag qf[4];
#pragma unroll
    for (int fm = 0; fm < 4; ++fm)
        qf[fm] = *reinterpret_cast<const bfrag*>(
            qB + (size_t)(q0 + fm * 16 + fr) * 32 + fq * 8);

    f4_t oacc[4][2];
    float rs[4][4];
#pragma unroll
    for (int fm = 0; fm < 4; ++fm) {
        oacc[fm][0] = (f4_t)0.f;
        oacc[fm][1] = (f4_t)0.f;
#pragma unroll
        for (int j = 0; j < 4; ++j) rs[fm][j] = 0.f;
    }
    const f4_t zero4 = (f4_t)0.f;
    const float qsl = 0.17677669529663687f * 1.4426950408889634f;

    for (int kt = 0; kt < 8; ++kt) {
        bfrag kf0 = *reinterpret_cast<const bfrag*>(
            kB + (size_t)(kt * 32 + fr) * 32 + fq * 8);
        bfrag kf1 = *reinterpret_cast<const bfrag*>(
            kB + (size_t)(kt * 32 + 16 + fr) * 32 + fq * 8);
        f4_t s0[4], s1[4];
#pragma unroll
        for (int fm = 0; fm < 4; ++fm) {
            s0[fm] = __builtin_amdgcn_mfma_f32_16x16x32_bf16(qf[fm], kf0, zero4, 0, 0, 0);
            s1[fm] = __builtin_amdgcn_mfma_f32_16x16x32_bf16(qf[fm], kf1, zero4, 0, 0, 0);
        }
#pragma unroll
        for (int fm = 0; fm < 4; ++fm) {
#pragma unroll
            for (int j = 0; j < 4; ++j) {
                const int row = fm * 16 + fq * 4 + j;
                ushort u0 = f2bf(exp2f(s0[fm][j] * qsl));
                ushort u1 = f2bf(exp2f(s1[fm][j] * qsl));
                Ps[w][row][fr] = u0;
                Ps[w][row][16 + fr] = u1;
                rs[fm][j] += bf2f(u0) + bf2f(u1);
            }
        }
        bfrag vf0 = *reinterpret_cast<const bfrag*>(
            vB + (size_t)fr * 256 + kt * 32 + fq * 8);
        bfrag vf1 = *reinterpret_cast<const bfrag*>(
            vB + (size_t)(16 + fr) * 256 + kt * 32 + fq * 8);
        bfrag pf[4];
#pragma unroll
        for (int fm = 0; fm < 4; ++fm)
            pf[fm] = *reinterpret_cast<const bfrag*>(&Ps[w][fm * 16 + fr][fq * 8]);
#pragma unroll
        for (int fm = 0; fm < 4; ++fm) {
            oacc[fm][0] = __builtin_amdgcn_mfma_f32_16x16x32_bf16(pf[fm], vf0, oacc[fm][0], 0, 0, 0);
            oacc[fm][1] = __builtin_amdgcn_mfma_f32_16x16x32_bf16(pf[fm], vf1, oacc[fm][1], 0, 0, 0);
        }
    }

#pragma unroll
    for (int fm = 0; fm < 4; ++fm)
#pragma unroll
        for (int j = 0; j < 4; ++j) {
            float r = rs[fm][j];
            r += __shfl_xor(r, 1);
            r += __shfl_xor(r, 2);
            r += __shfl_xor(r, 4);
            r += __shfl_xor(r, 8);
            rs[fm][j] = 1.f / r;
        }
    ushort* ob = o + (size_t)b * 65536 + hd * 32;
#pragma unroll
    for (int fm = 0; fm < 4; ++fm) {
        const int qrow = q0 + fm * 16 + fq * 4;
#pragma unroll
        for (int j = 0; j < 4; ++j) {
            const float inv = rs[fm][j];
            ob[(size_t)(qrow + j) * 256 + fr] = f2bf(oacc[fm][0][j] * inv);
            ob[(size_t)(qrow + j) * 256 + 16 + fr] = f2bf(oacc[fm][1][j] * inv);
        }
    }
}

// ---------------------------------------------------------------------------
// Transpose+convert for message passing.
// ---------------------------------------------------------------------------
__global__ __launch_bounds__(256) void k_xpose_bmm(
    const float* __restrict__ x, const float* __restrict__ nv,
    const float* __restrict__ ev, ushort* __restrict__ At,
    ushort* __restrict__ Xt) {
    const int b = blockIdx.z;
    const int k0 = blockIdx.x * 64, i0 = blockIdx.y * 64;
    __shared__ float TA[64][65];
    __shared__ float TX[64][65];
    const size_t bb = (size_t)b * 65536;
    const int tid = threadIdx.x;
    const int lr = tid >> 4, lc = (tid & 15) * 4;
#pragma unroll
    for (int l = 0; l < 4; ++l) {
        const int row = lr + l * 16;
        const size_t gidx = bb + (size_t)(k0 + row) * 256 + i0 + lc;
        float4 n4 = *reinterpret_cast<const float4*>(nv + gidx);
        float4 e4 = *reinterpret_cast<const float4*>(ev + gidx);
        float4 x4 = *reinterpret_cast<const float4*>(x + gidx);
        TA[row][lc] = 0.5f * (n4.x + e4.x);
        TA[row][lc + 1] = 0.5f * (n4.y + e4.y);
        TA[row][lc + 2] = 0.5f * (n4.z + e4.z);
        TA[row][lc + 3] = 0.5f * (n4.w + e4.w);
        TX[row][lc] = x4.x;
        TX[row][lc + 1] = x4.y;
        TX[row][lc + 2] = x4.z;
        TX[row][lc + 3] = x4.w;
    }
    __syncthreads();
    const int i = tid & 63, kk = (tid >> 6) * 16;
    bfrag a0, a1, x0, x1;
#pragma unroll
    for (int e = 0; e < 8; ++e) {
        a0[e] = (short)f2bf(TA[kk + e][i]);
        a1[e] = (short)f2bf(TA[kk + 8 + e][i]);
        x0[e] = (short)f2bf(TX[kk + e][i]);
        x1[e] = (short)f2bf(TX[kk + 8 + e][i]);
    }
    const size_t o = bb + (size_t)(i0 + i) * 256 + k0 + kk;
    *reinterpret_cast<bfrag*>(At + o) = a0;
    *reinterpret_cast<bfrag*>(At + o + 8) = a1;
    *reinterpret_cast<bfrag*>(Xt + o) = x0;
    *reinterpret_cast<bfrag*>(Xt + o + 8) = x1;
}

// ---------------------------------------------------------------------------
// Row stats on yT[b][r][t] (contiguous rows): mean, 1/(std+1e-8).
// grid (4, B), 256 threads: thread -> (row = tid>>2, part = tid&3).
// ---------------------------------------------------------------------------
__global__ __launch_bounds__(256) void k_rowstats(const ushort* __restrict__ yT,
                                                  float* __restrict__ stats) {
    const int b = blockIdx.y;
    const int r = blockIdx.x * 64 + (threadIdx.x >> 2);
    const int part = threadIdx.x & 3;
    const ushort* row = yT + (size_t)b * 65536 + (size_t)r * 256 + part * 64;
    float s = 0.f, q = 0.f;
#pragma unroll
    for (int i = 0; i < 8; ++i) {
        bfrag v = reinterpret_cast<const bfrag*>(row)[i];
#pragma unroll
        for (int e = 0; e < 8; ++e) {
            float f = bf2f((ushort)v[e]);
            s += f;
            q += f * f;
        }
    }
    s += __shfl_xor(s, 1); q += __shfl_xor(q, 1);
    s += __shfl_xor(s, 2); q += __shfl_xor(q, 2);
    if (part == 0) {
        const float mean = s * (1.f / 256.f);
        const float var = (q - s * mean) * (1.f / 255.f);
        const float stdv = sqrtf(fmaxf(var, 0.f));
        stats[b * 512 + r] = mean;
        stats[b * 512 + 256 + r] = 1.f / (stdv + 1e-8f);
    }
}

// ---------------------------------------------------------------------------
// Correlation SYRK on raw yT with exact normalization epilogue:
// corr_ij = (acc - 256 mu_i mu_j) * (1/255) * istd_i * istd_j, nan->0, clip.
// Same core as k_mm (A=B=yT, batched). grid (4, 2, B).
// ---------------------------------------------------------------------------
__global__ __launch_bounds__(256) void k_corr2(
    const ushort* __restrict__ A, const float* __restrict__ stats,
    float* __restrict__ C) {
    __shared__ __align__(16) ushort As[64 * 72];
    __shared__ __align__(16) ushort Bs[128 * 72];
    const int tid = threadIdx.x;
    const int m0 = blockIdx.x * 64, n0 = blockIdx.y * 128;
    const size_t z = blockIdx.z;
    const int w = tid >> 6, lane = tid & 63;
    const int wm = w >> 1, wn = w & 1;
    const int fr = lane & 15, fq = lane >> 4;
    const int K = 256;

    const int arow = tid >> 2, akc = (tid & 3) * 16;
    const ushort* aS = A + z * 65536 + (size_t)(m0 + arow) * K + akc;
    ushort* aD = &As[arow * 72 + akc];
    const int brow = tid >> 1, bkc = (tid & 1) * 32;
    const ushort* bS = A + z * 65536 + (size_t)(n0 + brow) * K + bkc;
    ushort* bD = &Bs[brow * 72 + bkc];

    f4_t acc[2][4];
#pragma unroll
    for (int i = 0; i < 2; ++i)
#pragma unroll
        for (int j = 0; j < 4; ++j) acc[i][j] = (f4_t)0.f;

    bfrag ra0, ra1, rb0, rb1, rb2, rb3;
    {
        const bfrag* ap = reinterpret_cast<const bfrag*>(aS);
        ra0 = ap[0]; ra1 = ap[1];
        const bfrag* bp = reinterpret_cast<const bfrag*>(bS);
        rb0 = bp[0]; rb1 = bp[1]; rb2 = bp[2]; rb3 = bp[3];
    }

    for (int k0 = 0; k0 < K; k0 += 64) {
        reinterpret_cast<bfrag*>(aD)[0] = ra0;
        reinterpret_cast<bfrag*>(aD)[1] = ra1;
        reinterpret_cast<bfrag*>(bD)[0] = rb0;
        reinterpret_cast<bfrag*>(bD)[1] = rb1;
        reinterpret_cast<bfrag*>(bD)[2] = rb2;
        reinterpret_cast<bfrag*>(bD)[3] = rb3;
        __syncthreads();
        if (k0 + 64 < K) {
            const bfrag* ap = reinterpret_cast<const bfrag*>(aS + k0 + 64);
            ra0 = ap[0]; ra1 = ap[1];
            const bfrag* bp = reinterpret_cast<const bfrag*>(bS + k0 + 64);
            rb0 = bp[0]; rb1 = bp[1]; rb2 = bp[2]; rb3 = bp[3];
        }
#pragma unroll
        for (int ks = 0; ks < 2; ++ks) {
            const int kb = ks * 32 + fq * 8;
            bfrag af[2], bf[4];
#pragma unroll
            for (int fm = 0; fm < 2; ++fm)
                af[fm] = *reinterpret_cast<const bfrag*>(
                    &As[(wm * 32 + fm * 16 + fr) * 72 + kb]);
#pragma unroll
            for (int fn = 0; fn < 4; ++fn)
                bf[fn] = *reinterpret_cast<const bfrag*>(
                    &Bs[(wn * 64 + fn * 16 + fr) * 72 + kb]);
#pragma unroll
            for (int fm = 0; fm < 2; ++fm)
#pragma unroll
                for (int fn = 0; fn < 4; ++fn)
                    acc[fm][fn] = __builtin_amdgcn_mfma_f32_16x16x32_bf16(
                        bf[fn], af[fm], acc[fm][fn], 0, 0, 0);
        }
        __syncthreads();
    }

    const float* st = stats + z * 512;
#pragma unroll
    for (int fn = 0; fn < 4; ++fn) {
        const int col0 = n0 + wn * 64 + fn * 16 + fq * 4;
        const float4 muj = *reinterpret_cast<const float4*>(&st[col0]);
        const float4 isj = *reinterpret_cast<const float4*>(&st[256 + col0]);
#pragma unroll
        for (int fm = 0; fm < 2; ++fm) {
            const int row = m0 + wm * 32 + fm * 16 + fr;
            const float mui = st[row];
            const float isi = st[256 + row] * (1.f / 255.f);
            float v0 = (acc[fm][fn][0] - 256.f * mui * muj.x) * isi * isj.x;
            float v1 = (acc[fm][fn][1] - 256.f * mui * muj.y) * isi * isj.y;
            float v2 = (acc[fm][fn][2] - 256.f * mui * muj.z) * isi * isj.z;
            float v3 = (acc[fm][fn][3] - 256.f * mui * muj.w) * isi * isj.w;
            if (v0 != v0) v0 = 0.f;
            if (v1 != v1) v1 = 0.f;
            if (v2 != v2) v2 = 0.f;
            if (v3 != v3) v3 = 0.f;
            v0 = fminf(1.f, fmaxf(-1.f, v0));
            v1 = fminf(1.f, fmaxf(-1.f, v1));
            v2 = fminf(1.f, fmaxf(-1.f, v2));
            v3 = fminf(1.f, fmaxf(-1.f, v3));
            float4 fv = {v0, v1, v2, v3};
            *reinterpret_cast<float4*>(
                &C[z * 65536 + (size_t)row * 256 + col0]) = fv;
        }
    }
}

// ---------------------------------------------------------------------------
// Fused mean-pool + both MLP heads. One block per b, 512 threads.
// ---------------------------------------------------------------------------
__global__ __launch_bounds__(512) void k_poolhead(
    const ushort* __restrict__ h,
    const float* __restrict__ mw1, const float* __restrict__ mb1,
    const float* __restrict__ mg, const float* __restrict__ mbt,
    const float* __restrict__ mw2, const float* __restrict__ mb2,
    const float* __restrict__ lw1, const float* __restrict__ lb1,
    const float* __restrict__ lg, const float* __restrict__ lbt,
    const float* __restrict__ lw2, const float* __restrict__ lb2,
    float* __restrict__ outp) {
    const int b = blockIdx.x, tid = threadIdx.x;
    __shared__ float pp[2][256];
    __shared__ float pooled[256];
    __shared__ float rS[4], rQ[4];
    __shared__ float t1[2][128];

    {
        const int c = tid & 255, tc = tid >> 8;
        const ushort* hb = h + (size_t)b * 65536 + (size_t)tc * 128 * 256 + c;
        float s = 0.f;
        for (int t = 0; t < 128; ++t) s += bf2f(hb[(size_t)t * 256]);
        pp[tc][c] = s;
    }
    __syncthreads();
    if (tid < 256) pooled[tid] = (pp[0][tid] + pp[1][tid]) * (1.f / 256.f);
    __syncthreads();

    float a = 0.f;
    if (tid < 256) {
        const int hd = tid >> 7, u = tid & 127;
        const float* w1 = hd ? lw1 : mw1;
        const float* b1 = hd ? lb1 : mb1;
        a = b1[u];
        const float4* w1v = reinterpret_cast<const float4*>(w1 + (size_t)u * 256);
#pragma unroll 4
        for (int k4 = 0; k4 < 64; ++k4) {
            float4 wv = w1v[k4];
            float4 p = *reinterpret_cast<const float4*>(&pooled[k4 * 4]);
            a = dot4(p, wv, a);
        }
        float s = a, q = a * a;
#pragma unroll
        for (int m = 1; m < 64; m <<= 1) {
            s += __shfl_xor(s, m);
            q += __shfl_xor(q, m);
        }
        if ((tid & 63) == 0) { rS[tid >> 6] = s; rQ[tid >> 6] = q; }
    }
    __syncthreads();
    if (tid < 256) {
        const int hd = tid >> 7, u = tid & 127;
        const float* g = hd ? lg : mg;
        const float* bt = hd ? lbt : mbt;
        const float S = rS[hd * 2] + rS[hd * 2 + 1];
        const float Q = rQ[hd * 2] + rQ[hd * 2 + 1];
        const float mean = S * (1.f / 128.f);
        const float var = Q * (1.f / 128.f) - mean * mean;
        const float rstd = rsqrtf(fmaxf(var, 0.f) + 1e-5f);
        float v = (a - mean) * rstd * g[u] + bt[u];
        v = v >= 0.f ? v : 0.1f * v;
        t1[hd][u] = v;
    }
    __syncthreads();
    if (tid < 128) {
        const int hd = tid >> 6, ou = tid & 63;
        const float* w2 = hd ? lw2 : mw2;
        const float* b2 = hd ? lb2 : mb2;
        float o = b2[ou];
        const float* w2r = w2 + (size_t)ou * 128;
#pragma unroll 4
        for (int c = 0; c < 128; ++c) o = fmaf(t1[hd][c], w2r[c], o);
        outp[hd * 4096 + b * 64 + ou] = o;
    }
}

// ---------------------------------------------------------------------------
extern "C" void kernel_launch(void* const* d_in, const int* in_sizes, int n_in,
                              void* d_out, int out_size, void* d_ws, size_t ws_size,
                              hipStream_t stream) {
    const float* x = (const float*)d_in[0];
    const float* nv = (const float*)d_in[1];
    const float* ev = (const float*)d_in[2];
    const float* fp_w = (const float*)d_in[3];
    const float* fp_b = (const float*)d_in[4];
    const float* fp_g = (const float*)d_in[5];
    const float* fp_beta = (const float*)d_in[6];
    const float* qkv_w = (const float*)d_in[7];
    const float* qkv_b = (const float*)d_in[8];
    const float* aow = (const float*)d_in[9];
    const float* aob = (const float*)d_in[10];
    const float* ln1g = (const float*)d_in[11];
    const float* ln1b = (const float*)d_in[12];
    const float* f1w = (const float*)d_in[13];
    const float* f1b = (const float*)d_in[14];
    const float* f2w = (const float*)d_in[15];
    const float* f2b = (const float*)d_in[16];
    const float* ln2g = (const float*)d_in[17];
    const float* ln2b = (const float*)d_in[18];
    const float* outw = (const float*)d_in[19];
    const float* outb = (const float*)d_in[20];
    const float* muw1 = (const float*)d_in[21];
    const float* mub1 = (const float*)d_in[22];
    const float* mug = (const float*)d_in[23];
    const float* mubt = (const float*)d_in[24];
    const float* muw2 = (const float*)d_in[25];
    const float* mub2 = (const float*)d_in[26];
    const float* lvw1 = (const float*)d_in[27];
    const float* lvb1 = (const float*)d_in[28];
    const float* lvg = (const float*)d_in[29];
    const float* lvbt = (const float*)d_in[30];
    const float* lvw2 = (const float*)d_in[31];
    const float* lvb2 = (const float*)d_in[32];

    float* out = (float*)d_out;
    float* ws = (float*)d_ws;

    // fp32 stats region, then bf16 regions
    float* stats = ws;                     // [64][2][256] = 32768 floats
    ushort* ub = (ushort*)(ws + 32768);
    ushort* wh_bf = ub;                    // [16384,256]
    ushort* At = ub + 4194304;             // [64,256,256]
    ushort* Xt = ub + 8388608;             // [64,256,256]
    ushort* o_bf = ub + 16777216;          // [16384,256]; h0_bf alias
    ushort* h0_bf = o_bf;
    ushort* f1_bf = ub + 20971520;         // [16384,512]
    ushort* qb = ub + 29360128;            // [64,8,256,32]
    ushort* kb = ub + 33554432;            // [64,8,256,32]
    ushort* vtb = ub + 37748736;           // [64,8,32,256]
    ushort* yT = ub + 41943040;            // [64,256,256]
    ushort* wbf = ub + 46137344;           // weights, 1179648

    // 0. weights -> bf16
    k_cvt<<<576, 256, 0, stream>>>(fp_w, qkv_w, aow, f1w, f2w, outw, wbf);

    // 1. message passing: transpose inputs, batched MFMA -> h0_bf
    k_xpose_bmm<<<dim3(4, 4, BB), 256, 0, stream>>>(x, nv, ev, At, Xt);
    k_mm<0, false, true><<<dim3(4, 2, BB), 256, 0, stream>>>(
        At, Xt, nullptr, nullptr, h0_bf, 256, 256, 65536, 65536, 65536);

    // 2. feature proj + LN + leaky (fused) -> wh_bf
    k_mmln<1, false><<<512, 256, 0, stream>>>(
        h0_bf, wbf, fp_b, nullptr, fp_g, fp_beta, wh_bf, 256);

    // 3. transformer layers
    for (int l = 0; l < NLAYER; ++l) {
        k_mmqkv<<<dim3(256, 6), 256, 0, stream>>>(
            wh_bf, wbf + 65536 + (size_t)l * 196608, qkv_b + l * 768,
            qb, kb, vtb);
        k_attn3<<<dim3(8, BB), 256, 0, stream>>>(qb, kb, vtb, o_bf);
        k_mmln<0, true><<<512, 256, 0, stream>>>(
            o_bf, wbf + 458752 + (size_t)l * 65536, aob + l * 256,
            wh_bf, ln1g + l * 256, ln1b + l * 256, wh_bf, 256);
        k_mm<2, false, true><<<dim3(256, 4, 1), 256, 0, stream>>>(
            wh_bf, wbf + 589824 + (size_t)l * 131072, f1b + l * 512,
            nullptr, f1_bf, 256, 512, 0, 0, 0);
        k_mmln<0, true><<<512, 256, 0, stream>>>(
            f1_bf, wbf + 851968 + (size_t)l * 131072, f2b + l * 256,
            wh_bf, ln2g + l * 256, ln2b + l * 256, wh_bf, 512);
    }

    // 4. yT[b,r,t] = outw @ h[b]^T  (bias dropped: Pearson shift-invariant)
    k_mm<0, false, true><<<dim3(4, 2, BB), 256, 0, stream>>>(
        wbf + 1114112, wh_bf, nullptr, nullptr, yT, 256, 256, 0, 65536, 65536);

    // 5. Pearson: row stats, then SYRK with normalization epilogue
    k_rowstats<<<dim3(4, BB), 256, 0, stream>>>(yT, stats);
    k_corr2<<<dim3(4, 2, BB), 256, 0, stream>>>(yT, stats, out + 8192);

    // 6. fused pool + heads
    k_poolhead<<<BB, 512, 0, stream>>>(
        wh_bf, muw1, mub1, mug, mubt, muw2, mub2,
        lvw1, lvb1, lvg, lvbt, lvw2, lvb2, out);
}

// Round 10
// 236.348 us; speedup vs baseline: 1.1054x; 1.0117x over previous
//
#include <hip/hip_runtime.h>
#include <hip/hip_bf16.h>
#include <math.h>

#define BB 64
#define NLAYER 2

typedef __attribute__((ext_vector_type(8))) short bfrag;
typedef __attribute__((ext_vector_type(4))) float f4_t;

__device__ __forceinline__ float dot4(float4 a, float4 b, float acc) {
    acc = fmaf(a.x, b.x, acc);
    acc = fmaf(a.y, b.y, acc);
    acc = fmaf(a.z, b.z, acc);
    acc = fmaf(a.w, b.w, acc);
    return acc;
}

// fp32 -> bf16 round-to-nearest-even
__device__ __forceinline__ ushort f2bf(float f) {
    uint32_t u = __float_as_uint(f);
    uint32_t r = (u + 0x7FFFu + ((u >> 16) & 1u)) >> 16;
    return (ushort)r;
}
__device__ __forceinline__ float bf2f(ushort u) {
    return __uint_as_float(((uint32_t)u) << 16);
}

// async global->LDS DMA, 16B per lane; LDS dest = wave-uniform base + lane*16
__device__ __forceinline__ void gll16(const ushort* g, ushort* l) {
    __builtin_amdgcn_global_load_lds(
        (const __attribute__((address_space(1))) void*)g,
        (__attribute__((address_space(3))) void*)l, 16, 0, 0);
}

// ---------------------------------------------------------------------------
// Weight conversion fp32 -> bf16 into one ws region.
// offsets (elements): fp:0, qkv:65536, aow:458752, f1:589824, f2:851968,
// out:1114112; total 1179648. 2048 elems/block, 576 blocks.
// ---------------------------------------------------------------------------
__global__ __launch_bounds__(256) void k_cvt(
    const float* __restrict__ fp_w, const float* __restrict__ qkv_w,
    const float* __restrict__ aow, const float* __restrict__ f1w,
    const float* __restrict__ f2w, const float* __restrict__ outw,
    ushort* __restrict__ dst) {
    const int g = blockIdx.x;
    const size_t idx = (size_t)g * 2048 + threadIdx.x * 8;
    const float* src;
    size_t base;
    if (g < 32)       { src = fp_w;  base = 0; }
    else if (g < 224) { src = qkv_w; base = 65536; }
    else if (g < 288) { src = aow;   base = 458752; }
    else if (g < 416) { src = f1w;   base = 589824; }
    else if (g < 544) { src = f2w;   base = 851968; }
    else              { src = outw;  base = 1114112; }
    const float4* s4 = reinterpret_cast<const float4*>(src + (idx - base));
    float4 a = s4[0], b = s4[1];
    bfrag o;
    o[0] = (short)f2bf(a.x); o[1] = (short)f2bf(a.y);
    o[2] = (short)f2bf(a.z); o[3] = (short)f2bf(a.w);
    o[4] = (short)f2bf(b.x); o[5] = (short)f2bf(b.y);
    o[6] = (short)f2bf(b.z); o[7] = (short)f2bf(b.w);
    *reinterpret_cast<bfrag*>(dst + idx) = o;
}

// ---------------------------------------------------------------------------
// m97-style GEMM core pieces (BM=BN=128, BK=64, 4 waves, global_load_lds).
// LDS linear [128][64]. Wave w stages rows [w*32, w*32+32) of each tile in
// 4 x 1KB DMA issues. Fragments: row stride 64 elems.
// ---------------------------------------------------------------------------
#define MM97_STAGE(SRC, LDS, KSTRIDE)                                        \
    {                                                                        \
        _Pragma("unroll")                                                    \
        for (int c = 0; c < 4; ++c) {                                        \
            const int rr = (w << 5) + (c << 3) + (lane >> 3);                \
            gll16(SRC + (size_t)rr * (KSTRIDE) + k0 + ((lane & 7) << 3),     \
                  LDS + (((w << 5) + (c << 3)) << 6));                       \
        }                                                                    \
    }

#define MM97_COMPUTE()                                                       \
    _Pragma("unroll")                                                        \
    for (int ks = 0; ks < 2; ++ks) {                                         \
        const int kb = ks * 32 + fq * 8;                                     \
        bfrag af[4], bfv[4];                                                 \
        _Pragma("unroll")                                                    \
        for (int fm = 0; fm < 4; ++fm)                                       \
            af[fm] = *reinterpret_cast<const bfrag*>(                        \
                &As[((wm * 64 + fm * 16 + fr) << 6) + kb]);                  \
        _Pragma("unroll")                                                    \
        for (int fn = 0; fn < 4; ++fn)                                       \
            bfv[fn] = *reinterpret_cast<const bfrag*>(                       \
                &Bs[((wn * 64 + fn * 16 + fr) << 6) + kb]);                  \
        _Pragma("unroll")                                                    \
        for (int fm = 0; fm < 4; ++fm)                                       \
            _Pragma("unroll")                                                \
            for (int fn = 0; fn < 4; ++fn)                                   \
                acc[fm][fn] = __builtin_amdgcn_mfma_f32_16x16x32_bf16(       \
                    bfv[fn], af[fm], acc[fm][fn], 0, 0, 0);                  \
    }

// ---------------------------------------------------------------------------
// Generic m97 GEMM. C = A * B^T (+bias). EPI: 0 none, 2 relu.
// grid (M/128, N/128, nbatch).
// ---------------------------------------------------------------------------
template <int EPI, bool WF32, bool WBF>
__global__ __launch_bounds__(256) void k_mm97(
    const ushort* __restrict__ A, const ushort* __restrict__ B,
    const float* __restrict__ bias, float* __restrict__ C,
    ushort* __restrict__ Cb, int K, int N,
    size_t aStr, size_t bStr, size_t cStr) {
    __shared__ __align__(16) ushort As[128 * 64];
    __shared__ __align__(16) ushort Bs[128 * 64];
    const int tid = threadIdx.x;
    const int m0 = blockIdx.x * 128, n0 = blockIdx.y * 128;
    const size_t z = blockIdx.z;
    const int w = tid >> 6, lane = tid & 63;
    const int wm = w >> 1, wn = w & 1;
    const int fr = lane & 15, fq = lane >> 4;

    const ushort* aB = A + z * aStr + (size_t)m0 * K;
    const ushort* bB = B + z * bStr + (size_t)n0 * K;

    f4_t acc[4][4];
#pragma unroll
    for (int i = 0; i < 4; ++i)
#pragma unroll
        for (int j = 0; j < 4; ++j) acc[i][j] = (f4_t)0.f;

    for (int k0 = 0; k0 < K; k0 += 64) {
        MM97_STAGE(aB, As, K)
        MM97_STAGE(bB, Bs, K)
        __syncthreads();
        MM97_COMPUTE()
        __syncthreads();
    }

#pragma unroll
    for (int fn = 0; fn < 4; ++fn) {
        const int col0 = n0 + wn * 64 + fn * 16 + fq * 4;
        float4 bv = make_float4(0.f, 0.f, 0.f, 0.f);
        if (bias != nullptr)
            bv = *reinterpret_cast<const float4*>(&bias[col0]);
#pragma unroll
        for (int fm = 0; fm < 4; ++fm) {
            const int row = m0 + wm * 64 + fm * 16 + fr;
            float v0 = acc[fm][fn][0] + bv.x;
            float v1 = acc[fm][fn][1] + bv.y;
            float v2 = acc[fm][fn][2] + bv.z;
            float v3 = acc[fm][fn][3] + bv.w;
            if (EPI == 2) {
                v0 = fmaxf(v0, 0.f); v1 = fmaxf(v1, 0.f);
                v2 = fmaxf(v2, 0.f); v3 = fmaxf(v3, 0.f);
            }
            const size_t o = cStr * z + (size_t)row * N + col0;
            if (WF32) {
                float4 fv = {v0, v1, v2, v3};
                *reinterpret_cast<float4*>(&C[o]) = fv;
            }
            if (WBF) {
                ushort4 uv;
                uv.x = f2bf(v0); uv.y = f2bf(v1);
                uv.z = f2bf(v2); uv.w = f2bf(v3);
                *reinterpret_cast<ushort4*>(&Cb[o]) = uv;
            }
        }
    }
}

// ---------------------------------------------------------------------------
// qkv GEMM (m97 core): K=256, N=768, M=16384. Epilogue writes head-blocked
// layouts: qb/kb [b,h,t,32], vtb (V transposed) [b,h,32,t]. grid (128, 6).
// ---------------------------------------------------------------------------
__global__ __launch_bounds__(256) void k_mmqkv97(
    const ushort* __restrict__ A, const ushort* __restrict__ B,
    const float* __restrict__ bias, ushort* __restrict__ qb,
    ushort* __restrict__ kbuf, ushort* __restrict__ vtb) {
    __shared__ __align__(16) ushort As[128 * 64];
    __shared__ __align__(16) ushort Bs[128 * 64];
    const int tid = threadIdx.x;
    const int m0 = blockIdx.x * 128, n0 = blockIdx.y * 128;
    const int w = tid >> 6, lane = tid & 63;
    const int wm = w >> 1, wn = w & 1;
    const int fr = lane & 15, fq = lane >> 4;
    const int K = 256;

    const ushort* aB = A + (size_t)m0 * K;
    const ushort* bB = B + (size_t)n0 * K;

    f4_t acc[4][4];
#pragma unroll
    for (int i = 0; i < 4; ++i)
#pragma unroll
        for (int j = 0; j < 4; ++j) acc[i][j] = (f4_t)0.f;

    for (int k0 = 0; k0 < K; k0 += 64) {
        MM97_STAGE(aB, As, K)
        MM97_STAGE(bB, Bs, K)
        __syncthreads();
        MM97_COMPUTE()
        __syncthreads();
    }

    const int sec = n0 >> 8;  // 0=q, 1=k, 2=v (block-uniform)
#pragma unroll
    for (int fn = 0; fn < 4; ++fn) {
        const int col0 = n0 + wn * 64 + fn * 16 + fq * 4;
        const int hd = (col0 >> 5) & 7, dq = col0 & 31;
        const float4 bv = *reinterpret_cast<const float4*>(&bias[col0]);
#pragma unroll
        for (int fm = 0; fm < 4; ++fm) {
            const int row = m0 + wm * 64 + fm * 16 + fr;
            const int b = row >> 8, t = row & 255;
            const size_t bh = (size_t)b * 8 + hd;
            float v0 = acc[fm][fn][0] + bv.x;
            float v1 = acc[fm][fn][1] + bv.y;
            float v2 = acc[fm][fn][2] + bv.z;
            float v3 = acc[fm][fn][3] + bv.w;
            if (sec < 2) {
                ushort4 uv;
                uv.x = f2bf(v0); uv.y = f2bf(v1);
                uv.z = f2bf(v2); uv.w = f2bf(v3);
                ushort* dst = (sec == 0 ? qb : kbuf) + (bh * 256 + t) * 32 + dq;
                *reinterpret_cast<ushort4*>(dst) = uv;
            } else {
                ushort* dst = vtb + (bh * 32 + dq) * 256 + t;
                dst[0] = f2bf(v0);
                dst[256] = f2bf(v1);
                dst[512] = f2bf(v2);
                dst[768] = f2bf(v3);
            }
        }
    }
}

// ---------------------------------------------------------------------------
// Correlation SYRK (m97 core) on raw yT with normalization epilogue:
// corr_ij = (acc - 256 mu_i mu_j)*(1/255)*istd_i*istd_j, nan->0, clip.
// grid (2, 2, B).
// ---------------------------------------------------------------------------
__global__ __launch_bounds__(256) void k_corr97(
    const ushort* __restrict__ A, const float* __restrict__ stats,
    float* __restrict__ C) {
    __shared__ __align__(16) ushort As[128 * 64];
    __shared__ __align__(16) ushort Bs[128 * 64];
    const int tid = threadIdx.x;
    const int m0 = blockIdx.x * 128, n0 = blockIdx.y * 128;
    const size_t z = blockIdx.z;
    const int w = tid >> 6, lane = tid & 63;
    const int wm = w >> 1, wn = w & 1;
    const int fr = lane & 15, fq = lane >> 4;
    const int K = 256;

    const ushort* aB = A + z * 65536 + (size_t)m0 * K;
    const ushort* bB = A + z * 65536 + (size_t)n0 * K;

    f4_t acc[4][4];
#pragma unroll
    for (int i = 0; i < 4; ++i)
#pragma unroll
        for (int j = 0; j < 4; ++j) acc[i][j] = (f4_t)0.f;

    for (int k0 = 0; k0 < K; k0 += 64) {
        MM97_STAGE(aB, As, K)
        MM97_STAGE(bB, Bs, K)
        __syncthreads();
        MM97_COMPUTE()
        __syncthreads();
    }

    const float* st = stats + z * 512;
#pragma unroll
    for (int fn = 0; fn < 4; ++fn) {
        const int col0 = n0 + wn * 64 + fn * 16 + fq * 4;
        const float4 muj = *reinterpret_cast<const float4*>(&st[col0]);
        const float4 isj = *reinterpret_cast<const float4*>(&st[256 + col0]);
#pragma unroll
        for (int fm = 0; fm < 4; ++fm) {
            const int row = m0 + wm * 64 + fm * 16 + fr;
            const float mui = st[row];
            const float isi = st[256 + row] * (1.f / 255.f);
            float v0 = (acc[fm][fn][0] - 256.f * mui * muj.x) * isi * isj.x;
            float v1 = (acc[fm][fn][1] - 256.f * mui * muj.y) * isi * isj.y;
            float v2 = (acc[fm][fn][2] - 256.f * mui * muj.z) * isi * isj.z;
            float v3 = (acc[fm][fn][3] - 256.f * mui * muj.w) * isi * isj.w;
            if (v0 != v0) v0 = 0.f;
            if (v1 != v1) v1 = 0.f;
            if (v2 != v2) v2 = 0.f;
            if (v3 != v3) v3 = 0.f;
            v0 = fminf(1.f, fmaxf(-1.f, v0));
            v1 = fminf(1.f, fmaxf(-1.f, v1));
            v2 = fminf(1.f, fmaxf(-1.f, v2));
            v3 = fminf(1.f, fmaxf(-1.f, v3));
            float4 fv = {v0, v1, v2, v3};
            *reinterpret_cast<float4*>(
                &C[z * 65536 + (size_t)row * 256 + col0]) = fv;
        }
    }
}

// ---------------------------------------------------------------------------
// Fused GEMM + bias (+bf16 residual) + LayerNorm(256) (+leaky) -> bf16 only.
// BM=32, BN=256=N, 256 threads = 4 waves; register prefetch (unchanged).
// ---------------------------------------------------------------------------
template <int ACT, bool RES>
__global__ __launch_bounds__(256) void k_mmln(
    const ushort* __restrict__ A, const ushort* __restrict__ W,
    const float* __restrict__ bias, const ushort* __restrict__ res,
    const float* __restrict__ g, const float* __restrict__ bt,
    ushort* __restrict__ outb, int K) {
    __shared__ __align__(16) ushort As[32 * 72];
    __shared__ __align__(16) ushort Bs[256 * 72];
    __shared__ float redS[32][4];
    __shared__ float redQ[32][4];
    const int tid = threadIdx.x;
    const int m0 = blockIdx.x * 32;
    const int w = tid >> 6, lane = tid & 63;
    const int fr = lane & 15, fq = lane >> 4;

    const int arow = tid >> 3, akc = (tid & 7) * 8;
    const ushort* aS = A + (size_t)(m0 + arow) * K + akc;
    ushort* aD = &As[arow * 72 + akc];
    const int brow = tid >> 1, bkc = (tid & 1) * 32;
    const ushort* bS0 = W + (size_t)brow * K + bkc;
    const ushort* bS1 = W + (size_t)(brow + 128) * K + bkc;
    ushort* bD0 = &Bs[brow * 72 + bkc];
    ushort* bD1 = &Bs[(brow + 128) * 72 + bkc];

    f4_t acc[2][4];
#pragma unroll
    for (int i = 0; i < 2; ++i)
#pragma unroll
        for (int j = 0; j < 4; ++j) acc[i][j] = (f4_t)0.f;

    bfrag ra, rb0, rb1, rb2, rb3, rc0, rc1, rc2, rc3;
    {
        ra = *reinterpret_cast<const bfrag*>(aS);
        const bfrag* bp0 = reinterpret_cast<const bfrag*>(bS0);
        rb0 = bp0[0]; rb1 = bp0[1]; rb2 = bp0[2]; rb3 = bp0[3];
        const bfrag* bp1 = reinterpret_cast<const bfrag*>(bS1);
        rc0 = bp1[0]; rc1 = bp1[1]; rc2 = bp1[2]; rc3 = bp1[3];
    }

    for (int k0 = 0; k0 < K; k0 += 64) {
        *reinterpret_cast<bfrag*>(aD) = ra;
        reinterpret_cast<bfrag*>(bD0)[0] = rb0;
        reinterpret_cast<bfrag*>(bD0)[1] = rb1;
        reinterpret_cast<bfrag*>(bD0)[2] = rb2;
        reinterpret_cast<bfrag*>(bD0)[3] = rb3;
        reinterpret_cast<bfrag*>(bD1)[0] = rc0;
        reinterpret_cast<bfrag*>(bD1)[1] = rc1;
        reinterpret_cast<bfrag*>(bD1)[2] = rc2;
        reinterpret_cast<bfrag*>(bD1)[3] = rc3;
        __syncthreads();
        if (k0 + 64 < K) {
            ra = *reinterpret_cast<const bfrag*>(aS + k0 + 64);
            const bfrag* bp0 = reinterpret_cast<const bfrag*>(bS0 + k0 + 64);
            rb0 = bp0[0]; rb1 = bp0[1]; rb2 = bp0[2]; rb3 = bp0[3];
            const bfrag* bp1 = reinterpret_cast<const bfrag*>(bS1 + k0 + 64);
            rc0 = bp1[0]; rc1 = bp1[1]; rc2 = bp1[2]; rc3 = bp1[3];
        }
#pragma unroll
        for (int ks = 0; ks < 2; ++ks) {
            const int kb = ks * 32 + fq * 8;
            bfrag af[2], bf[4];
#pragma unroll
            for (int fm = 0; fm < 2; ++fm)
                af[fm] = *reinterpret_cast<const bfrag*>(
                    &As[(fm * 16 + fr) * 72 + kb]);
#pragma unroll
            for (int fn = 0; fn < 4; ++fn)
                bf[fn] = *reinterpret_cast<const bfrag*>(
                    &Bs[(w * 64 + fn * 16 + fr) * 72 + kb]);
#pragma unroll
            for (int fm = 0; fm < 2; ++fm)
#pragma unroll
                for (int fn = 0; fn < 4; ++fn)
                    acc[fm][fn] = __builtin_amdgcn_mfma_f32_16x16x32_bf16(
                        bf[fn], af[fm], acc[fm][fn], 0, 0, 0);
        }
        __syncthreads();
    }

#pragma unroll
    for (int fn = 0; fn < 4; ++fn) {
        const int col0 = w * 64 + fn * 16 + fq * 4;
        const float4 bv = *reinterpret_cast<const float4*>(&bias[col0]);
#pragma unroll
        for (int fm = 0; fm < 2; ++fm) {
            const int row = fm * 16 + fr;
            float r0 = 0.f, r1 = 0.f, r2 = 0.f, r3 = 0.f;
            if (RES) {
                ushort4 r4 = *reinterpret_cast<const ushort4*>(
                    &res[(size_t)(m0 + row) * 256 + col0]);
                r0 = bf2f(r4.x); r1 = bf2f(r4.y);
                r2 = bf2f(r4.z); r3 = bf2f(r4.w);
            }
            acc[fm][fn][0] += bv.x + r0;
            acc[fm][fn][1] += bv.y + r1;
            acc[fm][fn][2] += bv.z + r2;
            acc[fm][fn][3] += bv.w + r3;
        }
    }
#pragma unroll
    for (int fm = 0; fm < 2; ++fm) {
        float s = 0.f, q = 0.f;
#pragma unroll
        for (int fn = 0; fn < 4; ++fn)
#pragma unroll
            for (int j = 0; j < 4; ++j) {
                const float v = acc[fm][fn][j];
                s += v;
                q += v * v;
            }
        s += __shfl_xor(s, 16); q += __shfl_xor(q, 16);
        s += __shfl_xor(s, 32); q += __shfl_xor(q, 32);
        if (fq == 0) {
            redS[fm * 16 + fr][w] = s;
            redQ[fm * 16 + fr][w] = q;
        }
    }
    __syncthreads();
#pragma unroll
    for (int fm = 0; fm < 2; ++fm) {
        const int row = fm * 16 + fr;
        const float S = redS[row][0] + redS[row][1] + redS[row][2] + redS[row][3];
        const float Q = redQ[row][0] + redQ[row][1] + redQ[row][2] + redQ[row][3];
        const float mean = S * (1.f / 256.f);
        const float var = Q * (1.f / 256.f) - mean * mean;
        const float rstd = rsqrtf(fmaxf(var, 0.f) + 1e-5f);
        const size_t rowoff = (size_t)(m0 + row) * 256;
#pragma unroll
        for (int fn = 0; fn < 4; ++fn) {
            const int col0 = w * 64 + fn * 16 + fq * 4;
            const float4 g4 = *reinterpret_cast<const float4*>(&g[col0]);
            const float4 b4 = *reinterpret_cast<const float4*>(&bt[col0]);
            float v0 = (acc[fm][fn][0] - mean) * rstd * g4.x + b4.x;
            float v1 = (acc[fm][fn][1] - mean) * rstd * g4.y + b4.y;
            float v2 = (acc[fm][fn][2] - mean) * rstd * g4.z + b4.z;
            float v3 = (acc[fm][fn][3] - mean) * rstd * g4.w + b4.w;
            if (ACT == 1) {
                v0 = v0 >= 0.f ? v0 : 0.1f * v0;
                v1 = v1 >= 0.f ? v1 : 0.1f * v1;
                v2 = v2 >= 0.f ? v2 : 0.1f * v2;
                v3 = v3 >= 0.f ? v3 : 0.1f * v3;
            }
            ushort4 uv;
            uv.x = f2bf(v0); uv.y = f2bf(v1);
            uv.z = f2bf(v2); uv.w = f2bf(v3);
            *reinterpret_cast<ushort4*>(&outb[rowoff + col0]) = uv;
        }
    }
}

// ---------------------------------------------------------------------------
// Attention v3: Q/K from [b,h,t,32], V^T from [b,h,32,t] — operands loaded
// directly from global (L2-hot). LDS = P-bounce only.
// ---------------------------------------------------------------------------
__global__ __launch_bounds__(256) void k_attn3(
    const ushort* __restrict__ qb, const ushort* __restrict__ kbuf,
    const ushort* __restrict__ vtb, ushort* __restrict__ o) {
    __shared__ __align__(16) ushort Ps[4][64][40];
    const int hd = blockIdx.x, b = blockIdx.y;
    const size_t bh = (size_t)b * 8 + hd;
    const int tid = threadIdx.x;
    const int w = tid >> 6, lane = tid & 63;
    const int fr = lane & 15, fq = lane >> 4;

    const ushort* qB = qb + bh * 8192;
    const ushort* kB = kbuf + bh * 8192;
    const ushort* vB = vtb + bh * 8192;

    const int q0 = w * 64;
    bfrag qf[4];
#pragma unroll
    for (int fm = 0; fm < 4; ++fm)
        qf[fm] = *reinterpret_cast<const bfrag*>(
            qB + (size_t)(q0 + fm * 16 + fr) * 32 + fq * 8);

    f4_t oacc[4][2];
    float rs[4][4];
#pragma unroll
    for (int fm = 0; fm < 4; ++fm) {
        oacc[fm][0] = (f4_t)0.f;
        oacc[fm][1] = (f4_t)0.f;
#pragma unroll
        for (int j = 0; j < 4; ++j) rs[fm][j] = 0.f;
    }
    const f4_t zero4 = (f4_t)0.f;
    const float qsl = 0.17677669529663687f * 1.4426950408889634f;

    for (int kt = 0; kt < 8; ++kt) {
        bfrag kf0 = *reinterpret_cast<const bfrag*>(
            kB + (size_t)(kt * 32 + fr) * 32 + fq * 8);
        bfrag kf1 = *reinterpret_cast<const bfrag*>(
            kB + (size_t)(kt * 32 + 16 + fr) * 32 + fq * 8);
        f4_t s0[4], s1[4];
#pragma unroll
        for (int fm = 0; fm < 4; ++fm) {
            s0[fm] = __builtin_amdgcn_mfma_f32_16x16x32_bf16(qf[fm], kf0, zero4, 0, 0, 0);
            s1[fm] = __builtin_amdgcn_mfma_f32_16x16x32_bf16(qf[fm], kf1, zero4, 0, 0, 0);
        }
#pragma unroll
        for (int fm = 0; fm < 4; ++fm) {
#pragma unroll
            for (int j = 0; j < 4; ++j) {
                const int row = fm * 16 + fq * 4 + j;
                ushort u0 = f2bf(exp2f(s0[fm][j] * qsl));
                ushort u1 = f2bf(exp2f(s1[fm][j] * qsl));
                Ps[w][row][fr] = u0;
                Ps[w][row][16 + fr] = u1;
                rs[fm][j] += bf2f(u0) + bf2f(u1);
            }
        }
        bfrag vf0 = *reinterpret_cast<const bfrag*>(
            vB + (size_t)fr * 256 + kt * 32 + fq * 8);
        bfrag vf1 = *reinterpret_cast<const bfrag*>(
            vB + (size_t)(16 + fr) * 256 + kt * 32 + fq * 8);
        bfrag pf[4];
#pragma unroll
        for (int fm = 0; fm < 4; ++fm)
            pf[fm] = *reinterpret_cast<const bfrag*>(&Ps[w][fm * 16 + fr][fq * 8]);
#pragma unroll
        for (int fm = 0; fm < 4; ++fm) {
            oacc[fm][0] = __builtin_amdgcn_mfma_f32_16x16x32_bf16(pf[fm], vf0, oacc[fm][0], 0, 0, 0);
            oacc[fm][1] = __builtin_amdgcn_mfma_f32_16x16x32_bf16(pf[fm], vf1, oacc[fm][1], 0, 0, 0);
        }
    }

#pragma unroll
    for (int fm = 0; fm < 4; ++fm)
#pragma unroll
        for (int j = 0; j < 4; ++j) {
            float r = rs[fm][j];
            r += __shfl_xor(r, 1);
            r += __shfl_xor(r, 2);
            r += __shfl_xor(r, 4);
            r += __shfl_xor(r, 8);
            rs[fm][j] = 1.f / r;
        }
    ushort* ob = o + (size_t)b * 65536 + hd * 32;
#pragma unroll
    for (int fm = 0; fm < 4; ++fm) {
        const int qrow = q0 + fm * 16 + fq * 4;
#pragma unroll
        for (int j = 0; j < 4; ++j) {
            const float inv = rs[fm][j];
            ob[(size_t)(qrow + j) * 256 + fr] = f2bf(oacc[fm][0][j] * inv);
            ob[(size_t)(qrow + j) * 256 + 16 + fr] = f2bf(oacc[fm][1][j] * inv);
        }
    }
}

// ---------------------------------------------------------------------------
// Transpose+convert for message passing.
// ---------------------------------------------------------------------------
__global__ __launch_bounds__(256) void k_xpose_bmm(
    const float* __restrict__ x, const float* __restrict__ nv,
    const float* __restrict__ ev, ushort* __restrict__ At,
    ushort* __restrict__ Xt) {
    const int b = blockIdx.z;
    const int k0 = blockIdx.x * 64, i0 = blockIdx.y * 64;
    __shared__ float TA[64][65];
    __shared__ float TX[64][65];
    const size_t bb = (size_t)b * 65536;
    const int tid = threadIdx.x;
    const int lr = tid >> 4, lc = (tid & 15) * 4;
#pragma unroll
    for (int l = 0; l < 4; ++l) {
        const int row = lr + l * 16;
        const size_t gidx = bb + (size_t)(k0 + row) * 256 + i0 + lc;
        float4 n4 = *reinterpret_cast<const float4*>(nv + gidx);
        float4 e4 = *reinterpret_cast<const float4*>(ev + gidx);
        float4 x4 = *reinterpret_cast<const float4*>(x + gidx);
        TA[row][lc] = 0.5f * (n4.x + e4.x);
        TA[row][lc + 1] = 0.5f * (n4.y + e4.y);
        TA[row][lc + 2] = 0.5f * (n4.z + e4.z);
        TA[row][lc + 3] = 0.5f * (n4.w + e4.w);
        TX[row][lc] = x4.x;
        TX[row][lc + 1] = x4.y;
        TX[row][lc + 2] = x4.z;
        TX[row][lc + 3] = x4.w;
    }
    __syncthreads();
    const int i = tid & 63, kk = (tid >> 6) * 16;
    bfrag a0, a1, x0, x1;
#pragma unroll
    for (int e = 0; e < 8; ++e) {
        a0[e] = (short)f2bf(TA[kk + e][i]);
        a1[e] = (short)f2bf(TA[kk + 8 + e][i]);
        x0[e] = (short)f2bf(TX[kk + e][i]);
        x1[e] = (short)f2bf(TX[kk + 8 + e][i]);
    }
    const size_t o = bb + (size_t)(i0 + i) * 256 + k0 + kk;
    *reinterpret_cast<bfrag*>(At + o) = a0;
    *reinterpret_cast<bfrag*>(At + o + 8) = a1;
    *reinterpret_cast<bfrag*>(Xt + o) = x0;
    *reinterpret_cast<bfrag*>(Xt + o + 8) = x1;
}

// ---------------------------------------------------------------------------
// Row stats on yT[b][r][t]: mean, 1/(std+1e-8). grid (4, B), 256 threads.
// ---------------------------------------------------------------------------
__global__ __launch_bounds__(256) void k_rowstats(const ushort* __restrict__ yT,
                                                  float* __restrict__ stats) {
    const int b = blockIdx.y;
    const int r = blockIdx.x * 64 + (threadIdx.x >> 2);
    const int part = threadIdx.x & 3;
    const ushort* row = yT + (size_t)b * 65536 + (size_t)r * 256 + part * 64;
    float s = 0.f, q = 0.f;
#pragma unroll
    for (int i = 0; i < 8; ++i) {
        bfrag v = reinterpret_cast<const bfrag*>(row)[i];
#pragma unroll
        for (int e = 0; e < 8; ++e) {
            float f = bf2f((ushort)v[e]);
            s += f;
            q += f * f;
        }
    }
    s += __shfl_xor(s, 1); q += __shfl_xor(q, 1);
    s += __shfl_xor(s, 2); q += __shfl_xor(q, 2);
    if (part == 0) {
        const float mean = s * (1.f / 256.f);
        const float var = (q - s * mean) * (1.f / 255.f);
        const float stdv = sqrtf(fmaxf(var, 0.f));
        stats[b * 512 + r] = mean;
        stats[b * 512 + 256 + r] = 1.f / (stdv + 1e-8f);
    }
}

// ---------------------------------------------------------------------------
// Fused mean-pool + both MLP heads. One block per b, 512 threads.
// ---------------------------------------------------------------------------
__global__ __launch_bounds__(512) void k_poolhead(
    const ushort* __restrict__ h,
    const float* __restrict__ mw1, const float* __restrict__ mb1,
    const float* __restrict__ mg, const float* __restrict__ mbt,
    const float* __restrict__ mw2, const float* __restrict__ mb2,
    const float* __restrict__ lw1, const float* __restrict__ lb1,
    const float* __restrict__ lg, const float* __restrict__ lbt,
    const float* __restrict__ lw2, const float* __restrict__ lb2,
    float* __restrict__ outp) {
    const int b = blockIdx.x, tid = threadIdx.x;
    __shared__ float pp[2][256];
    __shared__ float pooled[256];
    __shared__ float rS[4], rQ[4];
    __shared__ float t1[2][128];

    {
        const int c = tid & 255, tc = tid >> 8;
        const ushort* hb = h + (size_t)b * 65536 + (size_t)tc * 128 * 256 + c;
        float s = 0.f;
        for (int t = 0; t < 128; ++t) s += bf2f(hb[(size_t)t * 256]);
        pp[tc][c] = s;
    }
    __syncthreads();
    if (tid < 256) pooled[tid] = (pp[0][tid] + pp[1][tid]) * (1.f / 256.f);
    __syncthreads();

    float a = 0.f;
    if (tid < 256) {
        const int hd = tid >> 7, u = tid & 127;
        const float* w1 = hd ? lw1 : mw1;
        const float* b1 = hd ? lb1 : mb1;
        a = b1[u];
        const float4* w1v = reinterpret_cast<const float4*>(w1 + (size_t)u * 256);
#pragma unroll 4
        for (int k4 = 0; k4 < 64; ++k4) {
            float4 wv = w1v[k4];
            float4 p = *reinterpret_cast<const float4*>(&pooled[k4 * 4]);
            a = dot4(p, wv, a);
        }
        float s = a, q = a * a;
#pragma unroll
        for (int m = 1; m < 64; m <<= 1) {
            s += __shfl_xor(s, m);
            q += __shfl_xor(q, m);
        }
        if ((tid & 63) == 0) { rS[tid >> 6] = s; rQ[tid >> 6] = q; }
    }
    __syncthreads();
    if (tid < 256) {
        const int hd = tid >> 7, u = tid & 127;
        const float* g = hd ? lg : mg;
        const float* bt = hd ? lbt : mbt;
        const float S = rS[hd * 2] + rS[hd * 2 + 1];
        const float Q = rQ[hd * 2] + rQ[hd * 2 + 1];
        const float mean = S * (1.f / 128.f);
        const float var = Q * (1.f / 128.f) - mean * mean;
        const float rstd = rsqrtf(fmaxf(var, 0.f) + 1e-5f);
        float v = (a - mean) * rstd * g[u] + bt[u];
        v = v >= 0.f ? v : 0.1f * v;
        t1[hd][u] = v;
    }
    __syncthreads();
    if (tid < 128) {
        const int hd = tid >> 6, ou = tid & 63;
        const float* w2 = hd ? lw2 : mw2;
        const float* b2 = hd ? lb2 : mb2;
        float o = b2[ou];
        const float* w2r = w2 + (size_t)ou * 128;
#pragma unroll 4
        for (int c = 0; c < 128; ++c) o = fmaf(t1[hd][c], w2r[c], o);
        outp[hd * 4096 + b * 64 + ou] = o;
    }
}

// ---------------------------------------------------------------------------
extern "C" void kernel_launch(void* const* d_in, const int* in_sizes, int n_in,
                              void* d_out, int out_size, void* d_ws, size_t ws_size,
                              hipStream_t stream) {
    const float* x = (const float*)d_in[0];
    const float* nv = (const float*)d_in[1];
    const float* ev = (const float*)d_in[2];
    const float* fp_w = (const float*)d_in[3];
    const float* fp_b = (const float*)d_in[4];
    const float* fp_g = (const float*)d_in[5];
    const float* fp_beta = (const float*)d_in[6];
    const float* qkv_w = (const float*)d_in[7];
    const float* qkv_b = (const float*)d_in[8];
    const float* aow = (const float*)d_in[9];
    const float* aob = (const float*)d_in[10];
    const float* ln1g = (const float*)d_in[11];
    const float* ln1b = (const float*)d_in[12];
    const float* f1w = (const float*)d_in[13];
    const float* f1b = (const float*)d_in[14];
    const float* f2w = (const float*)d_in[15];
    const float* f2b = (const float*)d_in[16];
    const float* ln2g = (const float*)d_in[17];
    const float* ln2b = (const float*)d_in[18];
    const float* outw = (const float*)d_in[19];
    const float* outb = (const float*)d_in[20];
    const float* muw1 = (const float*)d_in[21];
    const float* mub1 = (const float*)d_in[22];
    const float* mug = (const float*)d_in[23];
    const float* mubt = (const float*)d_in[24];
    const float* muw2 = (const float*)d_in[25];
    const float* mub2 = (const float*)d_in[26];
    const float* lvw1 = (const float*)d_in[27];
    const float* lvb1 = (const float*)d_in[28];
    const float* lvg = (const float*)d_in[29];
    const float* lvbt = (const float*)d_in[30];
    const float* lvw2 = (const float*)d_in[31];
    const float* lvb2 = (const float*)d_in[32];

    float* out = (float*)d_out;
    float* ws = (float*)d_ws;

    // fp32 stats region, then bf16 regions
    float* stats = ws;                     // [64][2][256] = 32768 floats
    ushort* ub = (ushort*)(ws + 32768);
    ushort* wh_bf = ub;                    // [16384,256]
    ushort* At = ub + 4194304;             // [64,256,256]
    ushort* Xt = ub + 8388608;             // [64,256,256]
    ushort* o_bf = ub + 16777216;          // [16384,256]; h0_bf alias
    ushort* h0_bf = o_bf;
    ushort* f1_bf = ub + 20971520;         // [16384,512]
    ushort* qb = ub + 29360128;            // [64,8,256,32]
    ushort* kb = ub + 33554432;            // [64,8,256,32]
    ushort* vtb = ub + 37748736;           // [64,8,32,256]
    ushort* yT = ub + 41943040;            // [64,256,256]
    ushort* wbf = ub + 46137344;           // weights, 1179648

    // 0. weights -> bf16
    k_cvt<<<576, 256, 0, stream>>>(fp_w, qkv_w, aow, f1w, f2w, outw, wbf);

    // 1. message passing: transpose inputs, batched MFMA -> h0_bf
    k_xpose_bmm<<<dim3(4, 4, BB), 256, 0, stream>>>(x, nv, ev, At, Xt);
    k_mm97<0, false, true><<<dim3(2, 2, BB), 256, 0, stream>>>(
        At, Xt, nullptr, nullptr, h0_bf, 256, 256, 65536, 65536, 65536);

    // 2. feature proj + LN + leaky (fused) -> wh_bf
    k_mmln<1, false><<<512, 256, 0, stream>>>(
        h0_bf, wbf, fp_b, nullptr, fp_g, fp_beta, wh_bf, 256);

    // 3. transformer layers
    for (int l = 0; l < NLAYER; ++l) {
        k_mmqkv97<<<dim3(128, 6), 256, 0, stream>>>(
            wh_bf, wbf + 65536 + (size_t)l * 196608, qkv_b + l * 768,
            qb, kb, vtb);
        k_attn3<<<dim3(8, BB), 256, 0, stream>>>(qb, kb, vtb, o_bf);
        k_mmln<0, true><<<512, 256, 0, stream>>>(
            o_bf, wbf + 458752 + (size_t)l * 65536, aob + l * 256,
            wh_bf, ln1g + l * 256, ln1b + l * 256, wh_bf, 256);
        k_mm97<2, false, true><<<dim3(128, 4, 1), 256, 0, stream>>>(
            wh_bf, wbf + 589824 + (size_t)l * 131072, f1b + l * 512,
            nullptr, f1_bf, 256, 512, 0, 0, 0);
        k_mmln<0, true><<<512, 256, 0, stream>>>(
            f1_bf, wbf + 851968 + (size_t)l * 131072, f2b + l * 256,
            wh_bf, ln2g + l * 256, ln2b + l * 256, wh_bf, 512);
    }

    // 4. yT[b,r,t] = outw @ h[b]^T  (bias dropped: Pearson shift-invariant)
    k_mm97<0, false, true><<<dim3(2, 2, BB), 256, 0, stream>>>(
        wbf + 1114112, wh_bf, nullptr, nullptr, yT, 256, 256, 0, 65536, 65536);

    // 5. Pearson: row stats, then SYRK with normalization epilogue
    k_rowstats<<<dim3(4, BB), 256, 0, stream>>>(yT, stats);
    k_corr97<<<dim3(2, 2, BB), 256, 0, stream>>>(yT, stats, out + 8192);

    // 6. fused pool + heads
    k_poolhead<<<BB, 512, 0, stream>>>(
        wh_bf, muw1, mub1, mug, mubt, muw2, mub2,
        lvw1, lvb1, lvg, lvbt, lvw2, lvb2, out);
}